// Round 14
// baseline (318.962 us; speedup 1.0000x reference)
//
#include <hip/hip_runtime.h>
#include <math.h>

#define DIN 128
#define HID 64
#define BKTSH 7      // 128 nodes per coarse bucket
#define NBKTCAP 512  // max buckets (n <= 65536)
#define CAPC 2560    // max edges per bucket for LDS fast path

typedef _Float16 h2 __attribute__((ext_vector_type(2)));
typedef _Float16 f16x8 __attribute__((ext_vector_type(8)));
typedef float f32x4 __attribute__((ext_vector_type(4)));
typedef float f32x2 __attribute__((ext_vector_type(2)));

__device__ inline unsigned short f2h(float f) {
  return __builtin_bit_cast(unsigned short, (_Float16)f);
}
__device__ inline h2 bch2(unsigned int u) { return __builtin_bit_cast(h2, u); }
__device__ inline unsigned int h2u(h2 x) { return __builtin_bit_cast(unsigned int, x); }
__device__ inline unsigned int pkrtz(float a, float b) {
  return __builtin_bit_cast(unsigned int, __builtin_amdgcn_cvt_pkrtz(a, b));
}
__device__ inline f16x8 bcf16x8(uint4 u) { return __builtin_bit_cast(f16x8, u); }

// ---------------- CSR build: 2-level bucket sort ----------------
// r13 lesson: random 4B scatter/atomic writes to global cost 64B/line with
// cross-XCD bouncing (k_scatter: 52 MB WRITE for 3.2 MB of data, 51 us).
// All scatters here land in block-private chunks or go through LDS.

// Pass A: per-block histogram over coarse buckets (dst >> BKTSH)
__global__ __launch_bounds__(256) void k_bktA(const int* __restrict__ dst,
                                              int* __restrict__ bhist,
                                              int nblkA, int E, int nbkt) {
  __shared__ int hist[NBKTCAP];
  int tid = threadIdx.x;
  for (int i = tid; i < nbkt; i += 256) hist[i] = 0;
  __syncthreads();
#pragma unroll
  for (int i = 0; i < 16; ++i) {
    int e = blockIdx.x * 4096 + i * 256 + tid;
    if (e < E) atomicAdd(&hist[dst[e] >> BKTSH], 1);
  }
  __syncthreads();
  for (int i = tid; i < nbkt; i += 256) bhist[i * nblkA + blockIdx.x] = hist[i];
}

// Scan: bucket totals -> bucket bases; bhist -> per-(bucket,block) positions
__global__ __launch_bounds__(512) void k_bktScan(int* __restrict__ bhist,
                                                 int* __restrict__ bktBase,
                                                 int* __restrict__ rowp,
                                                 int nblkA, int nbkt, int E, int n) {
  __shared__ int sc[512];
  int b = threadIdx.x;
  int s = 0;
  if (b < nbkt)
    for (int k = 0; k < nblkA; ++k) s += bhist[b * nblkA + k];
  sc[b] = s;
  __syncthreads();
  for (int d = 1; d < 512; d <<= 1) {
    int v = (b >= d) ? sc[b - d] : 0;
    __syncthreads();
    sc[b] += v;
    __syncthreads();
  }
  int base = sc[b] - s;  // exclusive
  if (b < nbkt) {
    bktBase[b] = base;
    int run = base;
    for (int k = 0; k < nblkA; ++k) {
      int c = bhist[b * nblkA + k];
      bhist[b * nblkA + k] = run;
      run += c;
    }
  }
  if (b == 0) {
    bktBase[nbkt] = E;
    rowp[n] = E;
  }
}

// Pass B: scatter (src,dst) records into block-private chunks per bucket
__global__ __launch_bounds__(256) void k_bktB(const int* __restrict__ src,
                                              const int* __restrict__ dst,
                                              const int* __restrict__ bpos,
                                              int2* __restrict__ ebuf,
                                              int nblkA, int E, int nbkt) {
  __shared__ int cur[NBKTCAP];
  int tid = threadIdx.x;
  for (int i = tid; i < nbkt; i += 256) cur[i] = bpos[i * nblkA + blockIdx.x];
  __syncthreads();
#pragma unroll
  for (int i = 0; i < 16; ++i) {
    int e = blockIdx.x * 4096 + i * 256 + tid;
    if (e < E) {
      int d = dst[e];
      int pos = atomicAdd(&cur[d >> BKTSH], 1);
      ebuf[pos] = make_int2(src[e], d);
    }
  }
}

// Pass C: per-bucket LDS counting-sort by exact node; writes rowp, deg, srcs
__global__ __launch_bounds__(256) void k_bktC(const int2* __restrict__ ebuf,
                                              const int* __restrict__ bktBase,
                                              int* __restrict__ rowp,
                                              int* __restrict__ deg,
                                              int* __restrict__ srcs, int n) {
  __shared__ int2 rec[CAPC];
  __shared__ int outv[CAPC];
  __shared__ int hist[128];
  __shared__ int sc[128];
  __shared__ int cur2[128];
  int b = blockIdx.x;
  int tid = threadIdx.x;
  int s0 = bktBase[b], s1 = bktBase[b + 1];
  int cnt = s1 - s0;
  int nodeBase = b << BKTSH;
  if (tid < 128) hist[tid] = 0;
  __syncthreads();
  bool fast = (cnt <= CAPC);
  if (fast) {
    for (int i = tid; i < cnt; i += 256) {
      int2 r = ebuf[s0 + i];
      rec[i] = r;
      atomicAdd(&hist[r.y & 127], 1);
    }
  } else {
    for (int i = tid; i < cnt; i += 256) atomicAdd(&hist[ebuf[s0 + i].y & 127], 1);
  }
  __syncthreads();
  if (tid < 128) sc[tid] = hist[tid];
  __syncthreads();
  for (int d = 1; d < 128; d <<= 1) {
    int v = (tid < 128 && tid >= d) ? sc[tid - d] : 0;
    __syncthreads();
    if (tid < 128) sc[tid] += v;
    __syncthreads();
  }
  if (tid < 128) {
    int excl = sc[tid] - hist[tid];
    int node = nodeBase + tid;
    if (node < n) {
      rowp[node] = s0 + excl;
      deg[node] = hist[tid];
    }
    cur2[tid] = excl;
  }
  __syncthreads();
  if (fast) {
    for (int i = tid; i < cnt; i += 256) {
      int2 r = rec[i];
      int pos = atomicAdd(&cur2[r.y & 127], 1);
      outv[pos] = r.x;
    }
    __syncthreads();
    for (int i = tid; i < cnt; i += 256) srcs[s0 + i] = outv[i];
  } else {  // overflow fallback (never taken for uniform-random graphs)
    for (int i = tid; i < cnt; i += 256) {
      int2 r = ebuf[s0 + i];
      int pos = atomicAdd(&cur2[r.y & 127], 1);
      srcs[s0 + pos] = r.x;
    }
  }
}

// ---------------- degree counting-sort (privatized LDS histograms) ----------------
__global__ __launch_bounds__(256) void k_dhist(const int* __restrict__ cnt,
                                               int* __restrict__ bhist, int n) {
  __shared__ int hist[64];
  int tid = threadIdx.x;
  if (tid < 64) hist[tid] = 0;
  __syncthreads();
  int base = blockIdx.x * 2048 + tid * 8;
#pragma unroll
  for (int i = 0; i < 8; ++i) {
    int idx = base + i;
    if (idx < n) atomicAdd(&hist[min(cnt[idx], 63)], 1);
  }
  __syncthreads();
  if (tid < 64) bhist[blockIdx.x * 64 + tid] = hist[tid];
}

__global__ void k_dscan2(const int* __restrict__ bhist, int* __restrict__ bbase,
                         int nblk) {
  int b = threadIdx.x;  // bucket 0..63, single wave
  int tot = 0;
  for (int blk = 0; blk < nblk; ++blk) tot += bhist[blk * 64 + b];
  int incl = tot;
#pragma unroll
  for (int d = 1; d < 64; d <<= 1) {
    int t = __shfl_up(incl, d, 64);
    if (b >= d) incl += t;
  }
  int run = incl - tot;
  for (int blk = 0; blk < nblk; ++blk) {
    bbase[blk * 64 + b] = run;
    run += bhist[blk * 64 + b];
  }
}

__global__ __launch_bounds__(256) void k_dscat2(const int* __restrict__ cnt,
                                                const int* __restrict__ bbase,
                                                int* __restrict__ perm, int n) {
  __shared__ int cur[64];
  int tid = threadIdx.x;
  if (tid < 64) cur[tid] = bbase[blockIdx.x * 64 + tid];
  __syncthreads();
  int base = blockIdx.x * 2048 + tid * 8;
#pragma unroll
  for (int i = 0; i < 8; ++i) {
    int idx = base + i;
    if (idx < n) {
      int pos = atomicAdd(&cur[min(cnt[idx], 63)], 1);
      perm[pos] = idx;
    }
  }
}

// ---------------- weight pre-pack: fp32 -> fp16 B-fragments ----------------
// WP layout (uint4): per layer l at l*5120: [0,1024) Bq(x0.125*log2e, 8ct x 2kk),
// [1024,2048) Bk, [2048,3072) Bv, [3072,4096) Bout (4ct x 4kk), [4096,4608) B1,
// [4608,5120) B2. Frag elem i = W[(kk*32+(lane>>4)*8+i)*ld + ct*16+(lane&15)].
__global__ __launch_bounds__(256) void k_wpack(
    const float* __restrict__ Wq, const float* __restrict__ Wk,
    const float* __restrict__ Wv, const float* __restrict__ Wout,
    const float* __restrict__ W1, const float* __restrict__ W2,
    uint4* __restrict__ P) {
  int t = blockIdx.x * 256 + threadIdx.x;  // 0..10239
  if (t >= 10240) return;
  int layer = t / 5120;
  int r = t - layer * 5120;
  const float* W;
  int idx, nkk, ld, base;
  float scale = 1.f;
  if (r < 1024) {
    W = Wq + layer * 64 * 128; idx = r; nkk = 2; ld = 128;
    scale = 0.125f * 1.44269504089f; base = 0;
  } else if (r < 2048) {
    W = Wk + layer * 64 * 128; idx = r - 1024; nkk = 2; ld = 128; base = 1024;
  } else if (r < 3072) {
    W = Wv + layer * 64 * 128; idx = r - 2048; nkk = 2; ld = 128; base = 2048;
  } else if (r < 4096) {
    W = Wout + layer * 128 * 64; idx = r - 3072; nkk = 4; ld = 64; base = 3072;
  } else if (r < 4608) {
    W = W1 + layer * 64 * 64; idx = r - 4096; nkk = 2; ld = 64; base = 4096;
  } else {
    W = W2 + layer * 64 * 64; idx = r - 4608; nkk = 2; ld = 64; base = 4608;
  }
  int lane = idx & 63;
  int g = idx >> 6;
  int ct = g / nkk, kk = g - ct * nkk;
  int lc = lane & 15, lg = lane >> 4;
  unsigned short o[8];
#pragma unroll
  for (int i = 0; i < 8; ++i)
    o[i] = f2h(W[(kk * 32 + lg * 8 + i) * ld + ct * 16 + lc] * scale);
  P[layer * 5120 + base + idx] = *(const uint4*)o;
}

// Bemb at WP[10240,11264) (4ct x 4kk, ld=64); Bo at WP[11264,11648) (3ct x 2kk,
// ld=40, zero-padded cols >= 40).
__global__ __launch_bounds__(256) void k_wpack2(const float* __restrict__ emb_w,
                                                const float* __restrict__ out_w,
                                                uint4* __restrict__ P) {
  int t = blockIdx.x * 256 + threadIdx.x;  // 0..1407
  if (t >= 1408) return;
  int lane, ct, kk, lc, lg;
  unsigned short o[8];
  if (t < 1024) {
    int idx = t;
    lane = idx & 63;
    int g = idx >> 6;
    ct = g >> 2; kk = g & 3;
    lc = lane & 15; lg = lane >> 4;
#pragma unroll
    for (int i = 0; i < 8; ++i)
      o[i] = f2h(emb_w[(kk * 32 + lg * 8 + i) * 64 + ct * 16 + lc]);
    P[10240 + idx] = *(const uint4*)o;
  } else {
    int idx = t - 1024;
    lane = idx & 63;
    int g = idx >> 6;
    ct = g >> 1; kk = g & 1;
    lc = lane & 15; lg = lane >> 4;
    int col = ct * 16 + lc;
#pragma unroll
    for (int i = 0; i < 8; ++i)
      o[i] = (col < 40) ? f2h(out_w[(kk * 32 + lg * 8 + i) * 40 + col]) : (unsigned short)0;
    P[11264 + idx] = *(const uint4*)o;
  }
}

// ---------------- shared QKV MFMA body ----------------
// Q -> Qh fp16 [N,128].  K,V -> KVf8: ushort[N,128], short c = {fp8 K[c], fp8 V[c]}.
__device__ inline void qkv_mfma(f16x8 af0, f16x8 af1, const uint4* __restrict__ Bq,
                                const uint4* __restrict__ Bk,
                                const uint4* __restrict__ Bv,
                                unsigned short* __restrict__ Qh,
                                unsigned short* __restrict__ KVf8, int nb, int n,
                                int lc, int lg) {
  // Q (fp16 out)
  {
    f32x4 acc[8] = {};
#pragma unroll
    for (int ct = 0; ct < 8; ++ct) {
      acc[ct] = __builtin_amdgcn_mfma_f32_16x16x32_f16(
          af0, bcf16x8(Bq[(ct * 2 + 0) * 64 + lg * 16 + lc]), acc[ct], 0, 0, 0);
      acc[ct] = __builtin_amdgcn_mfma_f32_16x16x32_f16(
          af1, bcf16x8(Bq[(ct * 2 + 1) * 64 + lg * 16 + lc]), acc[ct], 0, 0, 0);
    }
#pragma unroll
    for (int ct = 0; ct < 8; ++ct)
#pragma unroll
      for (int r = 0; r < 4; ++r) {
        int gn = nb + lg * 4 + r;
        if (gn < n) Qh[(size_t)gn * 128 + ct * 16 + lc] = f2h(acc[ct][r]);
      }
  }
  // K,V paired -> packed fp8 short per column
#pragma unroll
  for (int ct = 0; ct < 8; ++ct) {
    f32x4 ka = {}, va = {};
    ka = __builtin_amdgcn_mfma_f32_16x16x32_f16(
        af0, bcf16x8(Bk[(ct * 2 + 0) * 64 + lg * 16 + lc]), ka, 0, 0, 0);
    ka = __builtin_amdgcn_mfma_f32_16x16x32_f16(
        af1, bcf16x8(Bk[(ct * 2 + 1) * 64 + lg * 16 + lc]), ka, 0, 0, 0);
    va = __builtin_amdgcn_mfma_f32_16x16x32_f16(
        af0, bcf16x8(Bv[(ct * 2 + 0) * 64 + lg * 16 + lc]), va, 0, 0, 0);
    va = __builtin_amdgcn_mfma_f32_16x16x32_f16(
        af1, bcf16x8(Bv[(ct * 2 + 1) * 64 + lg * 16 + lc]), va, 0, 0, 0);
#pragma unroll
    for (int r = 0; r < 4; ++r) {
      unsigned int pw = (unsigned int)__builtin_amdgcn_cvt_pk_fp8_f32(
          ka[r], va[r], 0, false);  // byte0 = K, byte1 = V
      int gn = nb + lg * 4 + r;
      if (gn < n) KVf8[(size_t)gn * 128 + ct * 16 + lc] = (unsigned short)pw;
    }
  }
}

// ---------------- fused embedding + layer-0 QKV (MFMA, 16-node tile/wave) --------
__global__ __launch_bounds__(256) void k_embqkv(
    const float* __restrict__ x, const uint4* __restrict__ Bemb,
    const float* __restrict__ emb_b, float* __restrict__ h,
    const uint4* __restrict__ Bq, const uint4* __restrict__ Bk,
    const uint4* __restrict__ Bv, unsigned short* __restrict__ Qh,
    unsigned short* __restrict__ KVf8, int n) {
  __shared__ unsigned short red[4][16 * 88];
  int lane = threadIdx.x & 63, wv = threadIdx.x >> 6;
  int nb = (blockIdx.x * 4 + wv) * 16;
  if (nb >= n) return;
  int lc = lane & 15, lg = lane >> 4;

  int arow = (nb + lc < n) ? nb + lc : n - 1;
  const float* xr = x + (size_t)arow * 128;
  f16x8 ax[4];
#pragma unroll
  for (int kk = 0; kk < 4; ++kk) {
    float4 a = *(const float4*)(xr + kk * 32 + lg * 8);
    float4 b = *(const float4*)(xr + kk * 32 + lg * 8 + 4);
    unsigned short o[8] = {f2h(a.x), f2h(a.y), f2h(a.z), f2h(a.w),
                           f2h(b.x), f2h(b.y), f2h(b.z), f2h(b.w)};
    ax[kk] = bcf16x8(*(const uint4*)o);
  }
  f32x4 acc[4] = {};
#pragma unroll
  for (int kk = 0; kk < 4; ++kk)
#pragma unroll
    for (int ct = 0; ct < 4; ++ct)
      acc[ct] = __builtin_amdgcn_mfma_f32_16x16x32_f16(
          ax[kk], bcf16x8(Bemb[(ct * 4 + kk) * 64 + lane]), acc[ct], 0, 0, 0);
#pragma unroll
  for (int ct = 0; ct < 4; ++ct) {
    float bo = emb_b[ct * 16 + lc];
#pragma unroll
    for (int r = 0; r < 4; ++r) {
      float v = acc[ct][r] + bo;
      int gn = nb + lg * 4 + r;
      if (gn < n) h[(size_t)gn * 64 + ct * 16 + lc] = v;
      red[wv][(lg * 4 + r) * 88 + ct * 16 + lc] = f2h(v);
    }
  }
  f16x8 af0 = bcf16x8(*(const uint4*)&red[wv][lc * 88 + lg * 8]);
  f16x8 af1 = bcf16x8(*(const uint4*)&red[wv][lc * 88 + 32 + lg * 8]);
  qkv_mfma(af0, af1, Bq, Bk, Bv, Qh, KVf8, nb, n, lc, lg);
}

// ---------------- attention gather+softmax (fp8 KV, one 16B load/edge) ----------
__global__ __launch_bounds__(256) void k_attn(
    const unsigned short* __restrict__ Qh, const unsigned short* __restrict__ KVf8,
    const int* __restrict__ row, const int* __restrict__ srcs,
    const int* __restrict__ perm,
    unsigned short* __restrict__ aggrh, int n) {
  int lane = threadIdx.x & 63;
  int w = threadIdx.x >> 6;
  int idx = blockIdx.x * 4 + w;
  if (idx >= n) return;  // no barriers in this kernel
  int node = perm[idx];
  int sl = lane & 15, gi = lane >> 4;

  // Q cols sl*8..+8 as f32 (pre-scaled by 1/8*log2e in the Bq pack)
  uint4 qr = *(const uint4*)(Qh + (size_t)node * 128 + sl * 8);
  h2 qh0 = bch2(qr.x), qh1 = bch2(qr.y), qh2 = bch2(qr.z), qh3 = bch2(qr.w);
  float q0 = (float)qh0[0], q1 = (float)qh0[1], q2 = (float)qh1[0], q3 = (float)qh1[1];
  float q4 = (float)qh2[0], q5 = (float)qh2[1], q6 = (float)qh3[0], q7 = (float)qh3[1];

  int rs = row[node], re = row[node + 1];
  int deg = re - rs;
  float den = 0.f;
  float a0 = 0.f, a1 = 0.f, a2 = 0.f, a3 = 0.f;
  float a4 = 0.f, a5 = 0.f, a6 = 0.f, a7 = 0.f;

  if (deg > 0) {
    int iters = (deg + 3) >> 2;
    uint4 Kb[4];
    int sxb[4];
#pragma unroll
    for (int s = 0; s < 4; ++s) {
      if (s < iters) {
        int ei = rs + s * 4 + gi;
        int sx = (ei < re) ? srcs[ei] : srcs[rs];
        Kb[s] = *(const uint4*)(KVf8 + (size_t)sx * 128 + sl * 8);
      }
      int ei2 = rs + (s + 4) * 4 + gi;
      sxb[s] = (ei2 < re) ? srcs[ei2] : srcs[rs];
    }
    for (int it = 0; it < iters; it += 4) {
#pragma unroll
      for (int s = 0; s < 4; ++s) {
        int cit = it + s;
        if (cit < iters) {  // wave-uniform
          uint4 Wd = Kb[s];
          if (cit + 4 < iters) {
            Kb[s] = *(const uint4*)(KVf8 + (size_t)sxb[s] * 128 + sl * 8);
          }
          {
            int ei3 = rs + (cit + 8) * 4 + gi;
            sxb[s] = (ei3 < re) ? srcs[ei3] : srcs[rs];
          }
          // each word: bytes (0,1)=(K[c],V[c]) of even col, (2,3) odd col
          f32x2 p0 = __builtin_amdgcn_cvt_pk_f32_fp8(Wd.x, false);
          f32x2 p1 = __builtin_amdgcn_cvt_pk_f32_fp8(Wd.x, true);
          f32x2 p2 = __builtin_amdgcn_cvt_pk_f32_fp8(Wd.y, false);
          f32x2 p3 = __builtin_amdgcn_cvt_pk_f32_fp8(Wd.y, true);
          f32x2 p4 = __builtin_amdgcn_cvt_pk_f32_fp8(Wd.z, false);
          f32x2 p5 = __builtin_amdgcn_cvt_pk_f32_fp8(Wd.z, true);
          f32x2 p6 = __builtin_amdgcn_cvt_pk_f32_fp8(Wd.w, false);
          f32x2 p7 = __builtin_amdgcn_cvt_pk_f32_fp8(Wd.w, true);
          float sc = q0 * p0.x + q1 * p1.x + q2 * p2.x + q3 * p3.x +
                     q4 * p4.x + q5 * p5.x + q6 * p6.x + q7 * p7.x;
          sc += __shfl_xor(sc, 1, 64);
          sc += __shfl_xor(sc, 2, 64);
          sc += __shfl_xor(sc, 4, 64);  // octet-sum: head (sl>>3) score of edge gi
          bool ev = (rs + cit * 4 + gi) < re;
          float wgt = ev ? __builtin_amdgcn_exp2f(sc) : 0.f;
          den += wgt;
          a0 += wgt * p0.y;
          a1 += wgt * p1.y;
          a2 += wgt * p2.y;
          a3 += wgt * p3.y;
          a4 += wgt * p4.y;
          a5 += wgt * p5.y;
          a6 += wgt * p6.y;
          a7 += wgt * p7.y;
        }
      }
    }
  }
  // combine 4 edge groups
#pragma unroll
  for (int d = 16; d < 64; d <<= 1) {
    den += __shfl_xor(den, d, 64);
    a0 += __shfl_xor(a0, d, 64);
    a1 += __shfl_xor(a1, d, 64);
    a2 += __shfl_xor(a2, d, 64);
    a3 += __shfl_xor(a3, d, 64);
    a4 += __shfl_xor(a4, d, 64);
    a5 += __shfl_xor(a5, d, 64);
    a6 += __shfl_xor(a6, d, 64);
    a7 += __shfl_xor(a7, d, 64);
  }
  float inv = fminf(1.f / (den + 1e-16f), 60000.f);
  if (lane < 16) {
    uint4 o;
    o.x = pkrtz(a0 * inv, a1 * inv);
    o.y = pkrtz(a2 * inv, a3 * inv);
    o.z = pkrtz(a4 * inv, a5 * inv);
    o.w = pkrtz(a6 * inv, a7 * inv);
    *(uint4*)(aggrh + (size_t)node * 128 + sl * 8) = o;
  }
}

// ---------------- post (MFMA): Wout -> +res -> LN -> FFN, then:
// MODE 0: next-layer QKV from the final h.  MODE 1: logits + log_softmax.
template <int MODE>
__global__ __launch_bounds__(256) void k_post(
    const unsigned short* __restrict__ aggrh, float* __restrict__ h,
    const uint4* __restrict__ Bout, const float* __restrict__ bout,
    const float* __restrict__ lng, const float* __restrict__ lnb,
    const uint4* __restrict__ B1, const float* __restrict__ b1,
    const uint4* __restrict__ B2, const float* __restrict__ b2,
    const uint4* __restrict__ BqN, const uint4* __restrict__ BkN,
    const uint4* __restrict__ BvN, unsigned short* __restrict__ Qh,
    unsigned short* __restrict__ KVf8,
    const uint4* __restrict__ Bo, const float* __restrict__ out_b,
    float* __restrict__ out, int n) {
  __shared__ unsigned short red[4][16 * 88];
  int lane = threadIdx.x & 63, wv = threadIdx.x >> 6;
  int nb = (blockIdx.x * 4 + wv) * 16;
  if (nb >= n) return;  // no barriers in this kernel
  int lc = lane & 15, lg = lane >> 4;

  // GEMM1: O[16,64] = aggr[16,128] @ Wout
  f32x4 acc[4] = {};
  const uint4* arow_p = (const uint4*)(aggrh + (size_t)(nb + lc) * 128);
#pragma unroll
  for (int kk = 0; kk < 4; ++kk) {
    f16x8 af = bcf16x8(arow_p[kk * 4 + lg]);
#pragma unroll
    for (int ct = 0; ct < 4; ++ct)
      acc[ct] = __builtin_amdgcn_mfma_f32_16x16x32_f16(
          af, bcf16x8(Bout[(ct * 4 + kk) * 64 + lane]), acc[ct], 0, 0, 0);
  }

  // bias + residual + layernorm
  float x[4][4], hl[4][4];
#pragma unroll
  for (int ct = 0; ct < 4; ++ct) {
    float bo = bout[ct * 16 + lc];
#pragma unroll
    for (int r = 0; r < 4; ++r)
      x[r][ct] = acc[ct][r] + bo + h[(size_t)(nb + lg * 4 + r) * 64 + ct * 16 + lc];
  }
  float g[4], bb[4];
#pragma unroll
  for (int ct = 0; ct < 4; ++ct) {
    g[ct] = lng[ct * 16 + lc];
    bb[ct] = lnb[ct * 16 + lc];
  }
#pragma unroll
  for (int r = 0; r < 4; ++r) {
    float s = x[r][0] + x[r][1] + x[r][2] + x[r][3];
    s += __shfl_xor(s, 1, 64);
    s += __shfl_xor(s, 2, 64);
    s += __shfl_xor(s, 4, 64);
    s += __shfl_xor(s, 8, 64);
    float mu = s * (1.f / 64.f);
    float s2 = 0.f;
#pragma unroll
    for (int ct = 0; ct < 4; ++ct) {
      float xc = x[r][ct] - mu;
      s2 += xc * xc;
    }
    s2 += __shfl_xor(s2, 1, 64);
    s2 += __shfl_xor(s2, 2, 64);
    s2 += __shfl_xor(s2, 4, 64);
    s2 += __shfl_xor(s2, 8, 64);
    float inv = rsqrtf(s2 * (1.f / 64.f) + 1e-5f);
#pragma unroll
    for (int ct = 0; ct < 4; ++ct) {
      hl[r][ct] = (x[r][ct] - mu) * inv * g[ct] + bb[ct];
      red[wv][(lg * 4 + r) * 88 + ct * 16 + lc] = f2h(hl[r][ct]);
    }
  }

  // GEMM2: T = relu(hl @ W1 + b1)
  f32x4 acc2[4] = {};
#pragma unroll
  for (int kk = 0; kk < 2; ++kk) {
    f16x8 af = bcf16x8(*(const uint4*)&red[wv][lc * 88 + kk * 32 + lg * 8]);
#pragma unroll
    for (int ct = 0; ct < 4; ++ct)
      acc2[ct] = __builtin_amdgcn_mfma_f32_16x16x32_f16(
          af, bcf16x8(B1[(ct * 2 + kk) * 64 + lane]), acc2[ct], 0, 0, 0);
  }
#pragma unroll
  for (int ct = 0; ct < 4; ++ct) {
    float b1c = b1[ct * 16 + lc];
#pragma unroll
    for (int r = 0; r < 4; ++r)
      red[wv][(lg * 4 + r) * 88 + ct * 16 + lc] = f2h(fmaxf(acc2[ct][r] + b1c, 0.f));
  }

  // GEMM3: hfin = hl + T @ W2 + b2
  f32x4 acc3[4] = {};
#pragma unroll
  for (int kk = 0; kk < 2; ++kk) {
    f16x8 af = bcf16x8(*(const uint4*)&red[wv][lc * 88 + kk * 32 + lg * 8]);
#pragma unroll
    for (int ct = 0; ct < 4; ++ct)
      acc3[ct] = __builtin_amdgcn_mfma_f32_16x16x32_f16(
          af, bcf16x8(B2[(ct * 2 + kk) * 64 + lane]), acc3[ct], 0, 0, 0);
  }
#pragma unroll
  for (int ct = 0; ct < 4; ++ct) {
    float b2c = b2[ct * 16 + lc];
#pragma unroll
    for (int r = 0; r < 4; ++r) {
      float v = hl[r][ct] + acc3[ct][r] + b2c;
      int gn = nb + lg * 4 + r;
      if (MODE == 0 && gn < n) h[(size_t)gn * 64 + ct * 16 + lc] = v;
      red[wv][(lg * 4 + r) * 88 + ct * 16 + lc] = f2h(v);
    }
  }

  if (MODE == 0) {
    f16x8 af0 = bcf16x8(*(const uint4*)&red[wv][lc * 88 + lg * 8]);
    f16x8 af1 = bcf16x8(*(const uint4*)&red[wv][lc * 88 + 32 + lg * 8]);
    qkv_mfma(af0, af1, BqN, BkN, BvN, Qh, KVf8, nb, n, lc, lg);
  } else {
    // logits = hfin @ out_w + out_b (48 padded cols), then log_softmax over 40
    f32x4 lg4[3] = {};
#pragma unroll
    for (int kk = 0; kk < 2; ++kk) {
      f16x8 af = bcf16x8(*(const uint4*)&red[wv][lc * 88 + kk * 32 + lg * 8]);
#pragma unroll
      for (int ct = 0; ct < 3; ++ct)
        lg4[ct] = __builtin_amdgcn_mfma_f32_16x16x32_f16(
            af, bcf16x8(Bo[(ct * 2 + kk) * 64 + lane]), lg4[ct], 0, 0, 0);
    }
    float ob0 = out_b[lc], ob1 = out_b[16 + lc];
    float ob2 = (lc < 8) ? out_b[32 + lc] : 0.f;
#pragma unroll
    for (int r = 0; r < 4; ++r) {
      float l0 = lg4[0][r] + ob0;
      float l1 = lg4[1][r] + ob1;
      float l2 = (lc < 8) ? (lg4[2][r] + ob2) : -3.0e38f;
      float m = fmaxf(fmaxf(l0, l1), l2);
      m = fmaxf(m, __shfl_xor(m, 1, 64));
      m = fmaxf(m, __shfl_xor(m, 2, 64));
      m = fmaxf(m, __shfl_xor(m, 4, 64));
      m = fmaxf(m, __shfl_xor(m, 8, 64));
      float e = __expf(l0 - m) + __expf(l1 - m) + ((lc < 8) ? __expf(l2 - m) : 0.f);
      e += __shfl_xor(e, 1, 64);
      e += __shfl_xor(e, 2, 64);
      e += __shfl_xor(e, 4, 64);
      e += __shfl_xor(e, 8, 64);
      float ls = m + logf(e);
      int gn = nb + lg * 4 + r;
      if (gn < n) {
        out[(size_t)gn * 40 + lc] = l0 - ls;
        out[(size_t)gn * 40 + 16 + lc] = l1 - ls;
        if (lc < 8) out[(size_t)gn * 40 + 32 + lc] = l2 - ls;
      }
    }
  }
}

extern "C" void kernel_launch(void* const* d_in, const int* in_sizes, int n_in,
                              void* d_out, int out_size, void* d_ws, size_t ws_size,
                              hipStream_t stream) {
  const float* x     = (const float*)d_in[0];
  const int*   ei    = (const int*)d_in[1];
  const float* emb_w = (const float*)d_in[2];
  const float* emb_b = (const float*)d_in[3];
  const float* Wq    = (const float*)d_in[4];   // [2,64,128]
  const float* Wk    = (const float*)d_in[5];
  const float* Wv    = (const float*)d_in[6];
  const float* Wout  = (const float*)d_in[7];   // [2,128,64]
  const float* bout  = (const float*)d_in[8];
  const float* ln_g  = (const float*)d_in[9];
  const float* ln_b  = (const float*)d_in[10];
  const float* W1    = (const float*)d_in[11];  // [2,64,64]
  const float* b1    = (const float*)d_in[12];
  const float* W2    = (const float*)d_in[13];
  const float* b2    = (const float*)d_in[14];
  const float* out_w = (const float*)d_in[15];  // [64,40]
  const float* out_b = (const float*)d_in[16];
  float* out = (float*)d_out;

  const int n = in_sizes[0] / DIN;  // 50000
  const int E = in_sizes[1] / 2;    // 800000

  char* ws = (char*)d_ws;
  size_t off = 0;
  auto alloc = [&](size_t bytes) {
    void* p = ws + off;
    off = (off + bytes + 255) & ~(size_t)255;
    return p;
  };
  float* h              = (float*)alloc((size_t)n * 64 * 4);
  unsigned short* Qh    = (unsigned short*)alloc((size_t)n * 128 * 2);
  unsigned short* KVf8  = (unsigned short*)alloc((size_t)n * 128 * 2);
  unsigned short* aggrh = (unsigned short*)alloc((size_t)n * 128 * 2);
  int* rowp             = (int*)alloc((size_t)(n + 1) * 4);
  int* srcs             = (int*)alloc((size_t)E * 4);
  int* deg              = (int*)alloc((size_t)n * 4);
  int* perm             = (int*)alloc((size_t)n * 4);
  uint4* WP             = (uint4*)alloc((size_t)11648 * 16);
  int nblkA             = (E + 4095) / 4096;
  int nbkt              = (n + 127) >> BKTSH;
  int* bhist2           = (int*)alloc((size_t)NBKTCAP * nblkA * 4);
  int* bktBase          = (int*)alloc((size_t)(NBKTCAP + 1) * 4);
  int2* ebuf            = (int2*)alloc((size_t)E * 8);
  int nScanBlk          = (n + 2047) / 2048;
  int* bhist            = (int*)alloc((size_t)nScanBlk * 64 * 4);
  int* bbase            = (int*)alloc((size_t)nScanBlk * 64 * 4);

  const int* src = ei;
  const int* dst = ei + E;

  // CSR build via 2-level bucket sort (no random global scatters)
  k_bktA<<<nblkA, 256, 0, stream>>>(dst, bhist2, nblkA, E, nbkt);
  k_bktScan<<<1, 512, 0, stream>>>(bhist2, bktBase, rowp, nblkA, nbkt, E, n);
  k_bktB<<<nblkA, 256, 0, stream>>>(src, dst, bhist2, ebuf, nblkA, E, nbkt);
  k_bktC<<<nbkt, 256, 0, stream>>>(ebuf, bktBase, rowp, deg, srcs, n);
  // degree sort for load balance
  k_dhist<<<nScanBlk, 256, 0, stream>>>(deg, bhist, n);
  k_dscan2<<<1, 64, 0, stream>>>(bhist, bbase, nScanBlk);
  k_dscat2<<<nScanBlk, 256, 0, stream>>>(deg, bbase, perm, n);

  k_wpack<<<40, 256, 0, stream>>>(Wq, Wk, Wv, Wout, W1, W2, WP);
  k_wpack2<<<6, 256, 0, stream>>>(emb_w, out_w, WP);

  const uint4* L0 = WP;
  const uint4* L1 = WP + 5120;
  const uint4* Bemb = WP + 10240;
  const uint4* Bo = WP + 11264;

  // embedding + layer-0 QKV fused
  k_embqkv<<<(n + 63) / 64, 256, 0, stream>>>(x, Bemb, emb_b, h, L0, L0 + 1024,
                                              L0 + 2048, Qh, KVf8, n);

  // layer 0: attn -> post(+layer-1 QKV)
  k_attn<<<(n + 3) / 4, 256, 0, stream>>>(Qh, KVf8, rowp, srcs, perm, aggrh, n);
  k_post<0><<<(n + 63) / 64, 256, 0, stream>>>(
      aggrh, h, L0 + 3072, bout, ln_g, ln_b, L0 + 4096, b1, L0 + 4608, b2,
      L1, L1 + 1024, L1 + 2048, Qh, KVf8, nullptr, nullptr, nullptr, n);

  // layer 1: attn -> post(+logits/log_softmax)
  k_attn<<<(n + 3) / 4, 256, 0, stream>>>(Qh, KVf8, rowp, srcs, perm, aggrh, n);
  k_post<1><<<(n + 63) / 64, 256, 0, stream>>>(
      aggrh, h, L1 + 3072, bout + 64, ln_g + 64, ln_b + 64, L1 + 4096, b1 + 64,
      L1 + 4608, b2 + 64, nullptr, nullptr, nullptr, nullptr, nullptr,
      Bo, out_b, out, n);
}

// Round 15
// 203.071 us; speedup vs baseline: 1.5707x; 1.5707x over previous
//
#include <hip/hip_runtime.h>
#include <math.h>

#define DIN 128
#define HID 64
#define BKTSH 7      // 128 nodes per coarse bucket
#define NBKTCAP 512  // max buckets (n <= 65536)
#define CAPC 2560    // max edges per bucket for LDS fast path

typedef _Float16 h2 __attribute__((ext_vector_type(2)));
typedef _Float16 f16x8 __attribute__((ext_vector_type(8)));
typedef float f32x4 __attribute__((ext_vector_type(4)));
typedef float f32x2 __attribute__((ext_vector_type(2)));

__device__ inline unsigned short f2h(float f) {
  return __builtin_bit_cast(unsigned short, (_Float16)f);
}
__device__ inline h2 bch2(unsigned int u) { return __builtin_bit_cast(h2, u); }
__device__ inline unsigned int h2u(h2 x) { return __builtin_bit_cast(unsigned int, x); }
__device__ inline unsigned int pkrtz(float a, float b) {
  return __builtin_bit_cast(unsigned int, __builtin_amdgcn_cvt_pkrtz(a, b));
}
__device__ inline f16x8 bcf16x8(uint4 u) { return __builtin_bit_cast(f16x8, u); }

// ---------------- CSR build: 2-level bucket sort ----------------
// r13 lesson: random 4B global scatters cost 64B/line (52 MB WRITE for 3.2 MB).
// r14 lesson: never do an O(nbkt*nblkA) serial loop in a one-block kernel
// (k_bktScan was 126 us on one CU). Scans are wave-parallel below.

// Pass A: per-block histogram over coarse buckets (dst >> BKTSH)
__global__ __launch_bounds__(256) void k_bktA(const int* __restrict__ dst,
                                              int* __restrict__ bhist,
                                              int nblkA, int E, int nbkt) {
  __shared__ int hist[NBKTCAP];
  int tid = threadIdx.x;
  for (int i = tid; i < nbkt; i += 256) hist[i] = 0;
  __syncthreads();
#pragma unroll
  for (int i = 0; i < 16; ++i) {
    int e = blockIdx.x * 4096 + i * 256 + tid;
    if (e < E) atomicAdd(&hist[dst[e] >> BKTSH], 1);
  }
  __syncthreads();
  for (int i = tid; i < nbkt; i += 256) bhist[i * nblkA + blockIdx.x] = hist[i];
}

// Scan 1: per-bucket exclusive scan over its nblkA counts (one wave per bucket)
__global__ __launch_bounds__(256) void k_bktScan1(int* __restrict__ bhist,
                                                  int* __restrict__ btot,
                                                  int nblkA, int nbkt) {
  int wv = threadIdx.x >> 6, lane = threadIdx.x & 63;
  int b = blockIdx.x * 4 + wv;
  if (b >= nbkt) return;
  int* rowp = bhist + (size_t)b * nblkA;
  int carry = 0;
  for (int base = 0; base < nblkA; base += 64) {
    int i = base + lane;
    int v = (i < nblkA) ? rowp[i] : 0;
    int incl = v;
#pragma unroll
    for (int d = 1; d < 64; d <<= 1) {
      int t = __shfl_up(incl, d, 64);
      if (lane >= d) incl += t;
    }
    if (i < nblkA) rowp[i] = carry + incl - v;  // exclusive within bucket
    carry += __shfl(incl, 63, 64);
  }
  if (lane == 0) btot[b] = carry;
}

// Scan 2: exclusive scan over bucket totals -> bktBase (one 512-thread block)
__global__ __launch_bounds__(512) void k_bktScan2(const int* __restrict__ btot,
                                                  int* __restrict__ bktBase,
                                                  int* __restrict__ rowp,
                                                  int nbkt, int E, int n) {
  __shared__ int sc[512];
  int b = threadIdx.x;
  int s = (b < nbkt) ? btot[b] : 0;
  sc[b] = s;
  __syncthreads();
  for (int d = 1; d < 512; d <<= 1) {
    int v = (b >= d) ? sc[b - d] : 0;
    __syncthreads();
    sc[b] += v;
    __syncthreads();
  }
  if (b < nbkt) bktBase[b] = sc[b] - s;
  if (b == 0) {
    bktBase[nbkt] = E;
    rowp[n] = E;
  }
}

// Pass B: scatter (src,dst) records into block-private chunks per bucket
__global__ __launch_bounds__(256) void k_bktB(const int* __restrict__ src,
                                              const int* __restrict__ dst,
                                              const int* __restrict__ bpos,
                                              const int* __restrict__ bktBase,
                                              int2* __restrict__ ebuf,
                                              int nblkA, int E, int nbkt) {
  __shared__ int cur[NBKTCAP];
  int tid = threadIdx.x;
  for (int i = tid; i < nbkt; i += 256)
    cur[i] = bpos[i * nblkA + blockIdx.x] + bktBase[i];
  __syncthreads();
#pragma unroll
  for (int i = 0; i < 16; ++i) {
    int e = blockIdx.x * 4096 + i * 256 + tid;
    if (e < E) {
      int d = dst[e];
      int pos = atomicAdd(&cur[d >> BKTSH], 1);
      ebuf[pos] = make_int2(src[e], d);
    }
  }
}

// Pass C: per-bucket LDS counting-sort by exact node; writes rowp, deg, srcs
__global__ __launch_bounds__(256) void k_bktC(const int2* __restrict__ ebuf,
                                              const int* __restrict__ bktBase,
                                              int* __restrict__ rowp,
                                              int* __restrict__ deg,
                                              int* __restrict__ srcs, int n) {
  __shared__ int2 rec[CAPC];
  __shared__ int outv[CAPC];
  __shared__ int hist[128];
  __shared__ int sc[128];
  __shared__ int cur2[128];
  int b = blockIdx.x;
  int tid = threadIdx.x;
  int s0 = bktBase[b], s1 = bktBase[b + 1];
  int cnt = s1 - s0;
  int nodeBase = b << BKTSH;
  if (tid < 128) hist[tid] = 0;
  __syncthreads();
  bool fast = (cnt <= CAPC);
  if (fast) {
    for (int i = tid; i < cnt; i += 256) {
      int2 r = ebuf[s0 + i];
      rec[i] = r;
      atomicAdd(&hist[r.y & 127], 1);
    }
  } else {
    for (int i = tid; i < cnt; i += 256) atomicAdd(&hist[ebuf[s0 + i].y & 127], 1);
  }
  __syncthreads();
  if (tid < 128) sc[tid] = hist[tid];
  __syncthreads();
  for (int d = 1; d < 128; d <<= 1) {
    int v = (tid < 128 && tid >= d) ? sc[tid - d] : 0;
    __syncthreads();
    if (tid < 128) sc[tid] += v;
    __syncthreads();
  }
  if (tid < 128) {
    int excl = sc[tid] - hist[tid];
    int node = nodeBase + tid;
    if (node < n) {
      rowp[node] = s0 + excl;
      deg[node] = hist[tid];
    }
    cur2[tid] = excl;
  }
  __syncthreads();
  if (fast) {
    for (int i = tid; i < cnt; i += 256) {
      int2 r = rec[i];
      int pos = atomicAdd(&cur2[r.y & 127], 1);
      outv[pos] = r.x;
    }
    __syncthreads();
    for (int i = tid; i < cnt; i += 256) srcs[s0 + i] = outv[i];
  } else {  // overflow fallback (never taken for uniform-random graphs)
    for (int i = tid; i < cnt; i += 256) {
      int2 r = ebuf[s0 + i];
      int pos = atomicAdd(&cur2[r.y & 127], 1);
      srcs[s0 + pos] = r.x;
    }
  }
}

// ---------------- degree counting-sort (privatized LDS histograms) ----------------
__global__ __launch_bounds__(256) void k_dhist(const int* __restrict__ cnt,
                                               int* __restrict__ bhist, int n) {
  __shared__ int hist[64];
  int tid = threadIdx.x;
  if (tid < 64) hist[tid] = 0;
  __syncthreads();
  int base = blockIdx.x * 2048 + tid * 8;
#pragma unroll
  for (int i = 0; i < 8; ++i) {
    int idx = base + i;
    if (idx < n) atomicAdd(&hist[min(cnt[idx], 63)], 1);
  }
  __syncthreads();
  if (tid < 64) bhist[blockIdx.x * 64 + tid] = hist[tid];
}

__global__ void k_dscan2(const int* __restrict__ bhist, int* __restrict__ bbase,
                         int nblk) {
  int b = threadIdx.x;  // bucket 0..63, single wave
  int tot = 0;
  for (int blk = 0; blk < nblk; ++blk) tot += bhist[blk * 64 + b];
  int incl = tot;
#pragma unroll
  for (int d = 1; d < 64; d <<= 1) {
    int t = __shfl_up(incl, d, 64);
    if (b >= d) incl += t;
  }
  int run = incl - tot;
  for (int blk = 0; blk < nblk; ++blk) {
    bbase[blk * 64 + b] = run;
    run += bhist[blk * 64 + b];
  }
}

__global__ __launch_bounds__(256) void k_dscat2(const int* __restrict__ cnt,
                                                const int* __restrict__ bbase,
                                                int* __restrict__ perm, int n) {
  __shared__ int cur[64];
  int tid = threadIdx.x;
  if (tid < 64) cur[tid] = bbase[blockIdx.x * 64 + tid];
  __syncthreads();
  int base = blockIdx.x * 2048 + tid * 8;
#pragma unroll
  for (int i = 0; i < 8; ++i) {
    int idx = base + i;
    if (idx < n) {
      int pos = atomicAdd(&cur[min(cnt[idx], 63)], 1);
      perm[pos] = idx;
    }
  }
}

// ---------------- weight pre-pack: fp32 -> fp16 B-fragments ----------------
// WP layout (uint4): per layer l at l*5120: [0,1024) Bq(x0.125*log2e, 8ct x 2kk),
// [1024,2048) Bk, [2048,3072) Bv, [3072,4096) Bout (4ct x 4kk), [4096,4608) B1,
// [4608,5120) B2. Frag elem i = W[(kk*32+(lane>>4)*8+i)*ld + ct*16+(lane&15)].
__global__ __launch_bounds__(256) void k_wpack(
    const float* __restrict__ Wq, const float* __restrict__ Wk,
    const float* __restrict__ Wv, const float* __restrict__ Wout,
    const float* __restrict__ W1, const float* __restrict__ W2,
    uint4* __restrict__ P) {
  int t = blockIdx.x * 256 + threadIdx.x;  // 0..10239
  if (t >= 10240) return;
  int layer = t / 5120;
  int r = t - layer * 5120;
  const float* W;
  int idx, nkk, ld, base;
  float scale = 1.f;
  if (r < 1024) {
    W = Wq + layer * 64 * 128; idx = r; nkk = 2; ld = 128;
    scale = 0.125f * 1.44269504089f; base = 0;
  } else if (r < 2048) {
    W = Wk + layer * 64 * 128; idx = r - 1024; nkk = 2; ld = 128; base = 1024;
  } else if (r < 3072) {
    W = Wv + layer * 64 * 128; idx = r - 2048; nkk = 2; ld = 128; base = 2048;
  } else if (r < 4096) {
    W = Wout + layer * 128 * 64; idx = r - 3072; nkk = 4; ld = 64; base = 3072;
  } else if (r < 4608) {
    W = W1 + layer * 64 * 64; idx = r - 4096; nkk = 2; ld = 64; base = 4096;
  } else {
    W = W2 + layer * 64 * 64; idx = r - 4608; nkk = 2; ld = 64; base = 4608;
  }
  int lane = idx & 63;
  int g = idx >> 6;
  int ct = g / nkk, kk = g - ct * nkk;
  int lc = lane & 15, lg = lane >> 4;
  unsigned short o[8];
#pragma unroll
  for (int i = 0; i < 8; ++i)
    o[i] = f2h(W[(kk * 32 + lg * 8 + i) * ld + ct * 16 + lc] * scale);
  P[layer * 5120 + base + idx] = *(const uint4*)o;
}

// Bemb at WP[10240,11264) (4ct x 4kk, ld=64); Bo at WP[11264,11648) (3ct x 2kk,
// ld=40, zero-padded cols >= 40).
__global__ __launch_bounds__(256) void k_wpack2(const float* __restrict__ emb_w,
                                                const float* __restrict__ out_w,
                                                uint4* __restrict__ P) {
  int t = blockIdx.x * 256 + threadIdx.x;  // 0..1407
  if (t >= 1408) return;
  int lane, ct, kk, lc, lg;
  unsigned short o[8];
  if (t < 1024) {
    int idx = t;
    lane = idx & 63;
    int g = idx >> 6;
    ct = g >> 2; kk = g & 3;
    lc = lane & 15; lg = lane >> 4;
#pragma unroll
    for (int i = 0; i < 8; ++i)
      o[i] = f2h(emb_w[(kk * 32 + lg * 8 + i) * 64 + ct * 16 + lc]);
    P[10240 + idx] = *(const uint4*)o;
  } else {
    int idx = t - 1024;
    lane = idx & 63;
    int g = idx >> 6;
    ct = g >> 1; kk = g & 1;
    lc = lane & 15; lg = lane >> 4;
    int col = ct * 16 + lc;
#pragma unroll
    for (int i = 0; i < 8; ++i)
      o[i] = (col < 40) ? f2h(out_w[(kk * 32 + lg * 8 + i) * 40 + col]) : (unsigned short)0;
    P[11264 + idx] = *(const uint4*)o;
  }
}

// ---------------- shared QKV MFMA body ----------------
// Q -> Qh fp16 [N,128].  K,V -> KVf8: ushort[N,128], short c = {fp8 K[c], fp8 V[c]}.
__device__ inline void qkv_mfma(f16x8 af0, f16x8 af1, const uint4* __restrict__ Bq,
                                const uint4* __restrict__ Bk,
                                const uint4* __restrict__ Bv,
                                unsigned short* __restrict__ Qh,
                                unsigned short* __restrict__ KVf8, int nb, int n,
                                int lc, int lg) {
  // Q (fp16 out)
  {
    f32x4 acc[8] = {};
#pragma unroll
    for (int ct = 0; ct < 8; ++ct) {
      acc[ct] = __builtin_amdgcn_mfma_f32_16x16x32_f16(
          af0, bcf16x8(Bq[(ct * 2 + 0) * 64 + lg * 16 + lc]), acc[ct], 0, 0, 0);
      acc[ct] = __builtin_amdgcn_mfma_f32_16x16x32_f16(
          af1, bcf16x8(Bq[(ct * 2 + 1) * 64 + lg * 16 + lc]), acc[ct], 0, 0, 0);
    }
#pragma unroll
    for (int ct = 0; ct < 8; ++ct)
#pragma unroll
      for (int r = 0; r < 4; ++r) {
        int gn = nb + lg * 4 + r;
        if (gn < n) Qh[(size_t)gn * 128 + ct * 16 + lc] = f2h(acc[ct][r]);
      }
  }
  // K,V paired -> packed fp8 short per column
#pragma unroll
  for (int ct = 0; ct < 8; ++ct) {
    f32x4 ka = {}, va = {};
    ka = __builtin_amdgcn_mfma_f32_16x16x32_f16(
        af0, bcf16x8(Bk[(ct * 2 + 0) * 64 + lg * 16 + lc]), ka, 0, 0, 0);
    ka = __builtin_amdgcn_mfma_f32_16x16x32_f16(
        af1, bcf16x8(Bk[(ct * 2 + 1) * 64 + lg * 16 + lc]), ka, 0, 0, 0);
    va = __builtin_amdgcn_mfma_f32_16x16x32_f16(
        af0, bcf16x8(Bv[(ct * 2 + 0) * 64 + lg * 16 + lc]), va, 0, 0, 0);
    va = __builtin_amdgcn_mfma_f32_16x16x32_f16(
        af1, bcf16x8(Bv[(ct * 2 + 1) * 64 + lg * 16 + lc]), va, 0, 0, 0);
#pragma unroll
    for (int r = 0; r < 4; ++r) {
      unsigned int pw = (unsigned int)__builtin_amdgcn_cvt_pk_fp8_f32(
          ka[r], va[r], 0, false);  // byte0 = K, byte1 = V
      int gn = nb + lg * 4 + r;
      if (gn < n) KVf8[(size_t)gn * 128 + ct * 16 + lc] = (unsigned short)pw;
    }
  }
}

// ---------------- fused embedding + layer-0 QKV (MFMA, 16-node tile/wave) --------
__global__ __launch_bounds__(256) void k_embqkv(
    const float* __restrict__ x, const uint4* __restrict__ Bemb,
    const float* __restrict__ emb_b, float* __restrict__ h,
    const uint4* __restrict__ Bq, const uint4* __restrict__ Bk,
    const uint4* __restrict__ Bv, unsigned short* __restrict__ Qh,
    unsigned short* __restrict__ KVf8, int n) {
  __shared__ unsigned short red[4][16 * 88];
  int lane = threadIdx.x & 63, wv = threadIdx.x >> 6;
  int nb = (blockIdx.x * 4 + wv) * 16;
  if (nb >= n) return;
  int lc = lane & 15, lg = lane >> 4;

  int arow = (nb + lc < n) ? nb + lc : n - 1;
  const float* xr = x + (size_t)arow * 128;
  f16x8 ax[4];
#pragma unroll
  for (int kk = 0; kk < 4; ++kk) {
    float4 a = *(const float4*)(xr + kk * 32 + lg * 8);
    float4 b = *(const float4*)(xr + kk * 32 + lg * 8 + 4);
    unsigned short o[8] = {f2h(a.x), f2h(a.y), f2h(a.z), f2h(a.w),
                           f2h(b.x), f2h(b.y), f2h(b.z), f2h(b.w)};
    ax[kk] = bcf16x8(*(const uint4*)o);
  }
  f32x4 acc[4] = {};
#pragma unroll
  for (int kk = 0; kk < 4; ++kk)
#pragma unroll
    for (int ct = 0; ct < 4; ++ct)
      acc[ct] = __builtin_amdgcn_mfma_f32_16x16x32_f16(
          ax[kk], bcf16x8(Bemb[(ct * 4 + kk) * 64 + lane]), acc[ct], 0, 0, 0);
#pragma unroll
  for (int ct = 0; ct < 4; ++ct) {
    float bo = emb_b[ct * 16 + lc];
#pragma unroll
    for (int r = 0; r < 4; ++r) {
      float v = acc[ct][r] + bo;
      int gn = nb + lg * 4 + r;
      if (gn < n) h[(size_t)gn * 64 + ct * 16 + lc] = v;
      red[wv][(lg * 4 + r) * 88 + ct * 16 + lc] = f2h(v);
    }
  }
  f16x8 af0 = bcf16x8(*(const uint4*)&red[wv][lc * 88 + lg * 8]);
  f16x8 af1 = bcf16x8(*(const uint4*)&red[wv][lc * 88 + 32 + lg * 8]);
  qkv_mfma(af0, af1, Bq, Bk, Bv, Qh, KVf8, nb, n, lc, lg);
}

// ---------------- attention gather+softmax (fp8 KV, one 16B load/edge) ----------
__global__ __launch_bounds__(256) void k_attn(
    const unsigned short* __restrict__ Qh, const unsigned short* __restrict__ KVf8,
    const int* __restrict__ row, const int* __restrict__ srcs,
    const int* __restrict__ perm,
    unsigned short* __restrict__ aggrh, int n) {
  int lane = threadIdx.x & 63;
  int w = threadIdx.x >> 6;
  int idx = blockIdx.x * 4 + w;
  if (idx >= n) return;  // no barriers in this kernel
  int node = perm[idx];
  int sl = lane & 15, gi = lane >> 4;

  // Q cols sl*8..+8 as f32 (pre-scaled by 1/8*log2e in the Bq pack)
  uint4 qr = *(const uint4*)(Qh + (size_t)node * 128 + sl * 8);
  h2 qh0 = bch2(qr.x), qh1 = bch2(qr.y), qh2 = bch2(qr.z), qh3 = bch2(qr.w);
  float q0 = (float)qh0[0], q1 = (float)qh0[1], q2 = (float)qh1[0], q3 = (float)qh1[1];
  float q4 = (float)qh2[0], q5 = (float)qh2[1], q6 = (float)qh3[0], q7 = (float)qh3[1];

  int rs = row[node], re = row[node + 1];
  int deg = re - rs;
  float den = 0.f;
  float a0 = 0.f, a1 = 0.f, a2 = 0.f, a3 = 0.f;
  float a4 = 0.f, a5 = 0.f, a6 = 0.f, a7 = 0.f;

  if (deg > 0) {
    int iters = (deg + 3) >> 2;
    uint4 Kb[4];
    int sxb[4];
#pragma unroll
    for (int s = 0; s < 4; ++s) {
      if (s < iters) {
        int ei = rs + s * 4 + gi;
        int sx = (ei < re) ? srcs[ei] : srcs[rs];
        Kb[s] = *(const uint4*)(KVf8 + (size_t)sx * 128 + sl * 8);
      }
      int ei2 = rs + (s + 4) * 4 + gi;
      sxb[s] = (ei2 < re) ? srcs[ei2] : srcs[rs];
    }
    for (int it = 0; it < iters; it += 4) {
#pragma unroll
      for (int s = 0; s < 4; ++s) {
        int cit = it + s;
        if (cit < iters) {  // wave-uniform
          uint4 Wd = Kb[s];
          if (cit + 4 < iters) {
            Kb[s] = *(const uint4*)(KVf8 + (size_t)sxb[s] * 128 + sl * 8);
          }
          {
            int ei3 = rs + (cit + 8) * 4 + gi;
            sxb[s] = (ei3 < re) ? srcs[ei3] : srcs[rs];
          }
          // each word: bytes (0,1)=(K[c],V[c]) of even col, (2,3) odd col
          f32x2 p0 = __builtin_amdgcn_cvt_pk_f32_fp8(Wd.x, false);
          f32x2 p1 = __builtin_amdgcn_cvt_pk_f32_fp8(Wd.x, true);
          f32x2 p2 = __builtin_amdgcn_cvt_pk_f32_fp8(Wd.y, false);
          f32x2 p3 = __builtin_amdgcn_cvt_pk_f32_fp8(Wd.y, true);
          f32x2 p4 = __builtin_amdgcn_cvt_pk_f32_fp8(Wd.z, false);
          f32x2 p5 = __builtin_amdgcn_cvt_pk_f32_fp8(Wd.z, true);
          f32x2 p6 = __builtin_amdgcn_cvt_pk_f32_fp8(Wd.w, false);
          f32x2 p7 = __builtin_amdgcn_cvt_pk_f32_fp8(Wd.w, true);
          float sc = q0 * p0.x + q1 * p1.x + q2 * p2.x + q3 * p3.x +
                     q4 * p4.x + q5 * p5.x + q6 * p6.x + q7 * p7.x;
          sc += __shfl_xor(sc, 1, 64);
          sc += __shfl_xor(sc, 2, 64);
          sc += __shfl_xor(sc, 4, 64);  // octet-sum: head (sl>>3) score of edge gi
          bool ev = (rs + cit * 4 + gi) < re;
          float wgt = ev ? __builtin_amdgcn_exp2f(sc) : 0.f;
          den += wgt;
          a0 += wgt * p0.y;
          a1 += wgt * p1.y;
          a2 += wgt * p2.y;
          a3 += wgt * p3.y;
          a4 += wgt * p4.y;
          a5 += wgt * p5.y;
          a6 += wgt * p6.y;
          a7 += wgt * p7.y;
        }
      }
    }
  }
  // combine 4 edge groups
#pragma unroll
  for (int d = 16; d < 64; d <<= 1) {
    den += __shfl_xor(den, d, 64);
    a0 += __shfl_xor(a0, d, 64);
    a1 += __shfl_xor(a1, d, 64);
    a2 += __shfl_xor(a2, d, 64);
    a3 += __shfl_xor(a3, d, 64);
    a4 += __shfl_xor(a4, d, 64);
    a5 += __shfl_xor(a5, d, 64);
    a6 += __shfl_xor(a6, d, 64);
    a7 += __shfl_xor(a7, d, 64);
  }
  float inv = fminf(1.f / (den + 1e-16f), 60000.f);
  if (lane < 16) {
    uint4 o;
    o.x = pkrtz(a0 * inv, a1 * inv);
    o.y = pkrtz(a2 * inv, a3 * inv);
    o.z = pkrtz(a4 * inv, a5 * inv);
    o.w = pkrtz(a6 * inv, a7 * inv);
    *(uint4*)(aggrh + (size_t)node * 128 + sl * 8) = o;
  }
}

// ---------------- post (MFMA): Wout -> +res -> LN -> FFN, then:
// MODE 0: next-layer QKV from the final h.  MODE 1: logits + log_softmax.
template <int MODE>
__global__ __launch_bounds__(256) void k_post(
    const unsigned short* __restrict__ aggrh, float* __restrict__ h,
    const uint4* __restrict__ Bout, const float* __restrict__ bout,
    const float* __restrict__ lng, const float* __restrict__ lnb,
    const uint4* __restrict__ B1, const float* __restrict__ b1,
    const uint4* __restrict__ B2, const float* __restrict__ b2,
    const uint4* __restrict__ BqN, const uint4* __restrict__ BkN,
    const uint4* __restrict__ BvN, unsigned short* __restrict__ Qh,
    unsigned short* __restrict__ KVf8,
    const uint4* __restrict__ Bo, const float* __restrict__ out_b,
    float* __restrict__ out, int n) {
  __shared__ unsigned short red[4][16 * 88];
  int lane = threadIdx.x & 63, wv = threadIdx.x >> 6;
  int nb = (blockIdx.x * 4 + wv) * 16;
  if (nb >= n) return;  // no barriers in this kernel
  int lc = lane & 15, lg = lane >> 4;

  // GEMM1: O[16,64] = aggr[16,128] @ Wout
  f32x4 acc[4] = {};
  const uint4* arow_p = (const uint4*)(aggrh + (size_t)(nb + lc) * 128);
#pragma unroll
  for (int kk = 0; kk < 4; ++kk) {
    f16x8 af = bcf16x8(arow_p[kk * 4 + lg]);
#pragma unroll
    for (int ct = 0; ct < 4; ++ct)
      acc[ct] = __builtin_amdgcn_mfma_f32_16x16x32_f16(
          af, bcf16x8(Bout[(ct * 4 + kk) * 64 + lane]), acc[ct], 0, 0, 0);
  }

  // bias + residual + layernorm
  float x[4][4], hl[4][4];
#pragma unroll
  for (int ct = 0; ct < 4; ++ct) {
    float bo = bout[ct * 16 + lc];
#pragma unroll
    for (int r = 0; r < 4; ++r)
      x[r][ct] = acc[ct][r] + bo + h[(size_t)(nb + lg * 4 + r) * 64 + ct * 16 + lc];
  }
  float g[4], bb[4];
#pragma unroll
  for (int ct = 0; ct < 4; ++ct) {
    g[ct] = lng[ct * 16 + lc];
    bb[ct] = lnb[ct * 16 + lc];
  }
#pragma unroll
  for (int r = 0; r < 4; ++r) {
    float s = x[r][0] + x[r][1] + x[r][2] + x[r][3];
    s += __shfl_xor(s, 1, 64);
    s += __shfl_xor(s, 2, 64);
    s += __shfl_xor(s, 4, 64);
    s += __shfl_xor(s, 8, 64);
    float mu = s * (1.f / 64.f);
    float s2 = 0.f;
#pragma unroll
    for (int ct = 0; ct < 4; ++ct) {
      float xc = x[r][ct] - mu;
      s2 += xc * xc;
    }
    s2 += __shfl_xor(s2, 1, 64);
    s2 += __shfl_xor(s2, 2, 64);
    s2 += __shfl_xor(s2, 4, 64);
    s2 += __shfl_xor(s2, 8, 64);
    float inv = rsqrtf(s2 * (1.f / 64.f) + 1e-5f);
#pragma unroll
    for (int ct = 0; ct < 4; ++ct) {
      hl[r][ct] = (x[r][ct] - mu) * inv * g[ct] + bb[ct];
      red[wv][(lg * 4 + r) * 88 + ct * 16 + lc] = f2h(hl[r][ct]);
    }
  }

  // GEMM2: T = relu(hl @ W1 + b1)
  f32x4 acc2[4] = {};
#pragma unroll
  for (int kk = 0; kk < 2; ++kk) {
    f16x8 af = bcf16x8(*(const uint4*)&red[wv][lc * 88 + kk * 32 + lg * 8]);
#pragma unroll
    for (int ct = 0; ct < 4; ++ct)
      acc2[ct] = __builtin_amdgcn_mfma_f32_16x16x32_f16(
          af, bcf16x8(B1[(ct * 2 + kk) * 64 + lane]), acc2[ct], 0, 0, 0);
  }
#pragma unroll
  for (int ct = 0; ct < 4; ++ct) {
    float b1c = b1[ct * 16 + lc];
#pragma unroll
    for (int r = 0; r < 4; ++r)
      red[wv][(lg * 4 + r) * 88 + ct * 16 + lc] = f2h(fmaxf(acc2[ct][r] + b1c, 0.f));
  }

  // GEMM3: hfin = hl + T @ W2 + b2
  f32x4 acc3[4] = {};
#pragma unroll
  for (int kk = 0; kk < 2; ++kk) {
    f16x8 af = bcf16x8(*(const uint4*)&red[wv][lc * 88 + kk * 32 + lg * 8]);
#pragma unroll
    for (int ct = 0; ct < 4; ++ct)
      acc3[ct] = __builtin_amdgcn_mfma_f32_16x16x32_f16(
          af, bcf16x8(B2[(ct * 2 + kk) * 64 + lane]), acc3[ct], 0, 0, 0);
  }
#pragma unroll
  for (int ct = 0; ct < 4; ++ct) {
    float b2c = b2[ct * 16 + lc];
#pragma unroll
    for (int r = 0; r < 4; ++r) {
      float v = hl[r][ct] + acc3[ct][r] + b2c;
      int gn = nb + lg * 4 + r;
      if (MODE == 0 && gn < n) h[(size_t)gn * 64 + ct * 16 + lc] = v;
      red[wv][(lg * 4 + r) * 88 + ct * 16 + lc] = f2h(v);
    }
  }

  if (MODE == 0) {
    f16x8 af0 = bcf16x8(*(const uint4*)&red[wv][lc * 88 + lg * 8]);
    f16x8 af1 = bcf16x8(*(const uint4*)&red[wv][lc * 88 + 32 + lg * 8]);
    qkv_mfma(af0, af1, BqN, BkN, BvN, Qh, KVf8, nb, n, lc, lg);
  } else {
    // logits = hfin @ out_w + out_b (48 padded cols), then log_softmax over 40
    f32x4 lg4[3] = {};
#pragma unroll
    for (int kk = 0; kk < 2; ++kk) {
      f16x8 af = bcf16x8(*(const uint4*)&red[wv][lc * 88 + kk * 32 + lg * 8]);
#pragma unroll
      for (int ct = 0; ct < 3; ++ct)
        lg4[ct] = __builtin_amdgcn_mfma_f32_16x16x32_f16(
            af, bcf16x8(Bo[(ct * 2 + kk) * 64 + lane]), lg4[ct], 0, 0, 0);
    }
    float ob0 = out_b[lc], ob1 = out_b[16 + lc];
    float ob2 = (lc < 8) ? out_b[32 + lc] : 0.f;
#pragma unroll
    for (int r = 0; r < 4; ++r) {
      float l0 = lg4[0][r] + ob0;
      float l1 = lg4[1][r] + ob1;
      float l2 = (lc < 8) ? (lg4[2][r] + ob2) : -3.0e38f;
      float m = fmaxf(fmaxf(l0, l1), l2);
      m = fmaxf(m, __shfl_xor(m, 1, 64));
      m = fmaxf(m, __shfl_xor(m, 2, 64));
      m = fmaxf(m, __shfl_xor(m, 4, 64));
      m = fmaxf(m, __shfl_xor(m, 8, 64));
      float e = __expf(l0 - m) + __expf(l1 - m) + ((lc < 8) ? __expf(l2 - m) : 0.f);
      e += __shfl_xor(e, 1, 64);
      e += __shfl_xor(e, 2, 64);
      e += __shfl_xor(e, 4, 64);
      e += __shfl_xor(e, 8, 64);
      float ls = m + logf(e);
      int gn = nb + lg * 4 + r;
      if (gn < n) {
        out[(size_t)gn * 40 + lc] = l0 - ls;
        out[(size_t)gn * 40 + 16 + lc] = l1 - ls;
        if (lc < 8) out[(size_t)gn * 40 + 32 + lc] = l2 - ls;
      }
    }
  }
}

extern "C" void kernel_launch(void* const* d_in, const int* in_sizes, int n_in,
                              void* d_out, int out_size, void* d_ws, size_t ws_size,
                              hipStream_t stream) {
  const float* x     = (const float*)d_in[0];
  const int*   ei    = (const int*)d_in[1];
  const float* emb_w = (const float*)d_in[2];
  const float* emb_b = (const float*)d_in[3];
  const float* Wq    = (const float*)d_in[4];   // [2,64,128]
  const float* Wk    = (const float*)d_in[5];
  const float* Wv    = (const float*)d_in[6];
  const float* Wout  = (const float*)d_in[7];   // [2,128,64]
  const float* bout  = (const float*)d_in[8];
  const float* ln_g  = (const float*)d_in[9];
  const float* ln_b  = (const float*)d_in[10];
  const float* W1    = (const float*)d_in[11];  // [2,64,64]
  const float* b1    = (const float*)d_in[12];
  const float* W2    = (const float*)d_in[13];
  const float* b2    = (const float*)d_in[14];
  const float* out_w = (const float*)d_in[15];  // [64,40]
  const float* out_b = (const float*)d_in[16];
  float* out = (float*)d_out;

  const int n = in_sizes[0] / DIN;  // 50000
  const int E = in_sizes[1] / 2;    // 800000

  char* ws = (char*)d_ws;
  size_t off = 0;
  auto alloc = [&](size_t bytes) {
    void* p = ws + off;
    off = (off + bytes + 255) & ~(size_t)255;
    return p;
  };
  float* h              = (float*)alloc((size_t)n * 64 * 4);
  unsigned short* Qh    = (unsigned short*)alloc((size_t)n * 128 * 2);
  unsigned short* KVf8  = (unsigned short*)alloc((size_t)n * 128 * 2);
  unsigned short* aggrh = (unsigned short*)alloc((size_t)n * 128 * 2);
  int* rowp             = (int*)alloc((size_t)(n + 1) * 4);
  int* srcs             = (int*)alloc((size_t)E * 4);
  int* deg              = (int*)alloc((size_t)n * 4);
  int* perm             = (int*)alloc((size_t)n * 4);
  uint4* WP             = (uint4*)alloc((size_t)11648 * 16);
  int nblkA             = (E + 4095) / 4096;
  int nbkt              = (n + 127) >> BKTSH;
  int* bhist2           = (int*)alloc((size_t)NBKTCAP * nblkA * 4);
  int* btot             = (int*)alloc((size_t)NBKTCAP * 4);
  int* bktBase          = (int*)alloc((size_t)(NBKTCAP + 1) * 4);
  int2* ebuf            = (int2*)alloc((size_t)E * 8);
  int nScanBlk          = (n + 2047) / 2048;
  int* bhist            = (int*)alloc((size_t)nScanBlk * 64 * 4);
  int* bbase            = (int*)alloc((size_t)nScanBlk * 64 * 4);

  const int* src = ei;
  const int* dst = ei + E;

  // CSR build via 2-level bucket sort (no random global scatters; wave-parallel scans)
  k_bktA<<<nblkA, 256, 0, stream>>>(dst, bhist2, nblkA, E, nbkt);
  k_bktScan1<<<(nbkt + 3) / 4, 256, 0, stream>>>(bhist2, btot, nblkA, nbkt);
  k_bktScan2<<<1, 512, 0, stream>>>(btot, bktBase, rowp, nbkt, E, n);
  k_bktB<<<nblkA, 256, 0, stream>>>(src, dst, bhist2, bktBase, ebuf, nblkA, E, nbkt);
  k_bktC<<<nbkt, 256, 0, stream>>>(ebuf, bktBase, rowp, deg, srcs, n);
  // degree sort for load balance
  k_dhist<<<nScanBlk, 256, 0, stream>>>(deg, bhist, n);
  k_dscan2<<<1, 64, 0, stream>>>(bhist, bbase, nScanBlk);
  k_dscat2<<<nScanBlk, 256, 0, stream>>>(deg, bbase, perm, n);

  k_wpack<<<40, 256, 0, stream>>>(Wq, Wk, Wv, Wout, W1, W2, WP);
  k_wpack2<<<6, 256, 0, stream>>>(emb_w, out_w, WP);

  const uint4* L0 = WP;
  const uint4* L1 = WP + 5120;
  const uint4* Bemb = WP + 10240;
  const uint4* Bo = WP + 11264;

  // embedding + layer-0 QKV fused
  k_embqkv<<<(n + 63) / 64, 256, 0, stream>>>(x, Bemb, emb_b, h, L0, L0 + 1024,
                                              L0 + 2048, Qh, KVf8, n);

  // layer 0: attn -> post(+layer-1 QKV)
  k_attn<<<(n + 3) / 4, 256, 0, stream>>>(Qh, KVf8, rowp, srcs, perm, aggrh, n);
  k_post<0><<<(n + 63) / 64, 256, 0, stream>>>(
      aggrh, h, L0 + 3072, bout, ln_g, ln_b, L0 + 4096, b1, L0 + 4608, b2,
      L1, L1 + 1024, L1 + 2048, Qh, KVf8, nullptr, nullptr, nullptr, n);

  // layer 1: attn -> post(+logits/log_softmax)
  k_attn<<<(n + 3) / 4, 256, 0, stream>>>(Qh, KVf8, rowp, srcs, perm, aggrh, n);
  k_post<1><<<(n + 63) / 64, 256, 0, stream>>>(
      aggrh, h, L1 + 3072, bout + 64, ln_g + 64, ln_b + 64, L1 + 4096, b1 + 64,
      L1 + 4608, b2 + 64, nullptr, nullptr, nullptr, nullptr, nullptr,
      Bo, out_b, out, n);
}

// Round 16
// 186.203 us; speedup vs baseline: 1.7130x; 1.0906x over previous
//
#include <hip/hip_runtime.h>
#include <math.h>

#define DIN 128
#define HID 64
#define BKTSH 7      // 128 nodes per coarse bucket
#define NBKTCAP 512  // max buckets (n <= 65536)
#define CAPC 2560    // max edges per bucket for LDS fast path

typedef _Float16 h2 __attribute__((ext_vector_type(2)));
typedef _Float16 f16x8 __attribute__((ext_vector_type(8)));
typedef float f32x4 __attribute__((ext_vector_type(4)));
typedef float f32x2 __attribute__((ext_vector_type(2)));

__device__ inline unsigned short f2h(float f) {
  return __builtin_bit_cast(unsigned short, (_Float16)f);
}
__device__ inline h2 bch2(unsigned int u) { return __builtin_bit_cast(h2, u); }
__device__ inline unsigned int pkrtz(float a, float b) {
  return __builtin_bit_cast(unsigned int, __builtin_amdgcn_cvt_pkrtz(a, b));
}
__device__ inline f16x8 bcf16x8(uint4 u) { return __builtin_bit_cast(f16x8, u); }

// ---------------- CSR build: 2-level bucket sort ----------------
// r13: random 4B global scatters cost 64B/line. r14: no serial one-block scans.

__global__ __launch_bounds__(256) void k_bktA(const int* __restrict__ dst,
                                              int* __restrict__ bhist,
                                              int nblkA, int E, int nbkt) {
  __shared__ int hist[NBKTCAP];
  int tid = threadIdx.x;
  for (int i = tid; i < nbkt; i += 256) hist[i] = 0;
  __syncthreads();
#pragma unroll
  for (int i = 0; i < 16; ++i) {
    int e = blockIdx.x * 4096 + i * 256 + tid;
    if (e < E) atomicAdd(&hist[dst[e] >> BKTSH], 1);
  }
  __syncthreads();
  for (int i = tid; i < nbkt; i += 256) bhist[i * nblkA + blockIdx.x] = hist[i];
}

__global__ __launch_bounds__(256) void k_bktScan1(int* __restrict__ bhist,
                                                  int* __restrict__ btot,
                                                  int nblkA, int nbkt) {
  int wv = threadIdx.x >> 6, lane = threadIdx.x & 63;
  int b = blockIdx.x * 4 + wv;
  if (b >= nbkt) return;
  int* rowp = bhist + (size_t)b * nblkA;
  int carry = 0;
  for (int base = 0; base < nblkA; base += 64) {
    int i = base + lane;
    int v = (i < nblkA) ? rowp[i] : 0;
    int incl = v;
#pragma unroll
    for (int d = 1; d < 64; d <<= 1) {
      int t = __shfl_up(incl, d, 64);
      if (lane >= d) incl += t;
    }
    if (i < nblkA) rowp[i] = carry + incl - v;
    carry += __shfl(incl, 63, 64);
  }
  if (lane == 0) btot[b] = carry;
}

__global__ __launch_bounds__(512) void k_bktScan2(const int* __restrict__ btot,
                                                  int* __restrict__ bktBase,
                                                  int* __restrict__ rowp,
                                                  int nbkt, int E, int n) {
  __shared__ int sc[512];
  int b = threadIdx.x;
  int s = (b < nbkt) ? btot[b] : 0;
  sc[b] = s;
  __syncthreads();
  for (int d = 1; d < 512; d <<= 1) {
    int v = (b >= d) ? sc[b - d] : 0;
    __syncthreads();
    sc[b] += v;
    __syncthreads();
  }
  if (b < nbkt) bktBase[b] = sc[b] - s;
  if (b == 0) {
    bktBase[nbkt] = E;
    rowp[n] = E;
  }
}

__global__ __launch_bounds__(256) void k_bktB(const int* __restrict__ src,
                                              const int* __restrict__ dst,
                                              const int* __restrict__ bpos,
                                              const int* __restrict__ bktBase,
                                              int2* __restrict__ ebuf,
                                              int nblkA, int E, int nbkt) {
  __shared__ int cur[NBKTCAP];
  int tid = threadIdx.x;
  for (int i = tid; i < nbkt; i += 256)
    cur[i] = bpos[i * nblkA + blockIdx.x] + bktBase[i];
  __syncthreads();
#pragma unroll
  for (int i = 0; i < 16; ++i) {
    int e = blockIdx.x * 4096 + i * 256 + tid;
    if (e < E) {
      int d = dst[e];
      int pos = atomicAdd(&cur[d >> BKTSH], 1);
      ebuf[pos] = make_int2(src[e], d);
    }
  }
}

__global__ __launch_bounds__(256) void k_bktC(const int2* __restrict__ ebuf,
                                              const int* __restrict__ bktBase,
                                              int* __restrict__ rowp,
                                              int* __restrict__ srcs, int n) {
  __shared__ int2 rec[CAPC];
  __shared__ int outv[CAPC];
  __shared__ int hist[128];
  __shared__ int sc[128];
  __shared__ int cur2[128];
  int b = blockIdx.x;
  int tid = threadIdx.x;
  int s0 = bktBase[b], s1 = bktBase[b + 1];
  int cnt = s1 - s0;
  int nodeBase = b << BKTSH;
  if (tid < 128) hist[tid] = 0;
  __syncthreads();
  bool fast = (cnt <= CAPC);
  if (fast) {
    for (int i = tid; i < cnt; i += 256) {
      int2 r = ebuf[s0 + i];
      rec[i] = r;
      atomicAdd(&hist[r.y & 127], 1);
    }
  } else {
    for (int i = tid; i < cnt; i += 256) atomicAdd(&hist[ebuf[s0 + i].y & 127], 1);
  }
  __syncthreads();
  if (tid < 128) sc[tid] = hist[tid];
  __syncthreads();
  for (int d = 1; d < 128; d <<= 1) {
    int v = (tid < 128 && tid >= d) ? sc[tid - d] : 0;
    __syncthreads();
    if (tid < 128) sc[tid] += v;
    __syncthreads();
  }
  if (tid < 128) {
    int excl = sc[tid] - hist[tid];
    int node = nodeBase + tid;
    if (node < n) rowp[node] = s0 + excl;
    cur2[tid] = excl;
  }
  __syncthreads();
  if (fast) {
    for (int i = tid; i < cnt; i += 256) {
      int2 r = rec[i];
      int pos = atomicAdd(&cur2[r.y & 127], 1);
      outv[pos] = r.x;
    }
    __syncthreads();
    for (int i = tid; i < cnt; i += 256) srcs[s0 + i] = outv[i];
  } else {
    for (int i = tid; i < cnt; i += 256) {
      int2 r = ebuf[s0 + i];
      int pos = atomicAdd(&cur2[r.y & 127], 1);
      srcs[s0 + pos] = r.x;
    }
  }
}

// ---------------- weight pre-pack: fp32 -> fp16 B-fragments ----------------
// WP layout (uint4) per layer l at l*5120: [0,1024) Bq(x0.125*log2e), [1024,2048) Bk,
// [2048,3072) Bv, [3072,4096) Bout (colperm'd k-map), [4096,4608) B1, [4608,5120) B2.
// aggr columns are stored permuted (p -> col cp(p) = head*64 + (p&3)*16 + ((p&63)>>2)),
// so Bout's k index compensates.
__global__ __launch_bounds__(256) void k_wpack(
    const float* __restrict__ Wq, const float* __restrict__ Wk,
    const float* __restrict__ Wv, const float* __restrict__ Wout,
    const float* __restrict__ W1, const float* __restrict__ W2,
    uint4* __restrict__ P) {
  int t = blockIdx.x * 256 + threadIdx.x;  // 0..10239
  if (t >= 10240) return;
  int layer = t / 5120;
  int r = t - layer * 5120;
  const float* W;
  int idx, nkk, ld, base;
  float scale = 1.f;
  bool permk = false;
  if (r < 1024) {
    W = Wq + layer * 64 * 128; idx = r; nkk = 2; ld = 128;
    scale = 0.125f * 1.44269504089f; base = 0;
  } else if (r < 2048) {
    W = Wk + layer * 64 * 128; idx = r - 1024; nkk = 2; ld = 128; base = 1024;
  } else if (r < 3072) {
    W = Wv + layer * 64 * 128; idx = r - 2048; nkk = 2; ld = 128; base = 2048;
  } else if (r < 4096) {
    W = Wout + layer * 128 * 64; idx = r - 3072; nkk = 4; ld = 64; base = 3072;
    permk = true;
  } else if (r < 4608) {
    W = W1 + layer * 64 * 64; idx = r - 4096; nkk = 2; ld = 64; base = 4096;
  } else {
    W = W2 + layer * 64 * 64; idx = r - 4608; nkk = 2; ld = 64; base = 4608;
  }
  int lane = idx & 63;
  int g = idx >> 6;
  int ct = g / nkk, kk = g - ct * nkk;
  int lc = lane & 15, lg = lane >> 4;
  unsigned short o[8];
#pragma unroll
  for (int i = 0; i < 8; ++i) {
    int rr = kk * 32 + lg * 8 + i;
    if (permk) {
      int bb = rr & 63;
      rr = (rr & 64) + (bb & 3) * 16 + (bb >> 2);
    }
    o[i] = f2h(W[rr * ld + ct * 16 + lc] * scale);
  }
  P[layer * 5120 + base + idx] = *(const uint4*)o;
}

// Bemb at WP[10240,11264); Bo at WP[11264,11648) (ld=40, zero-padded cols>=40).
__global__ __launch_bounds__(256) void k_wpack2(const float* __restrict__ emb_w,
                                                const float* __restrict__ out_w,
                                                uint4* __restrict__ P) {
  int t = blockIdx.x * 256 + threadIdx.x;  // 0..1407
  if (t >= 1408) return;
  int lane, ct, kk, lc, lg;
  unsigned short o[8];
  if (t < 1024) {
    int idx = t;
    lane = idx & 63;
    int g = idx >> 6;
    ct = g >> 2; kk = g & 3;
    lc = lane & 15; lg = lane >> 4;
#pragma unroll
    for (int i = 0; i < 8; ++i)
      o[i] = f2h(emb_w[(kk * 32 + lg * 8 + i) * 64 + ct * 16 + lc]);
    P[10240 + idx] = *(const uint4*)o;
  } else {
    int idx = t - 1024;
    lane = idx & 63;
    int g = idx >> 6;
    ct = g >> 1; kk = g & 1;
    lc = lane & 15; lg = lane >> 4;
    int col = ct * 16 + lc;
#pragma unroll
    for (int i = 0; i < 8; ++i)
      o[i] = (col < 40) ? f2h(out_w[(kk * 32 + lg * 8 + i) * 40 + col]) : (unsigned short)0;
    P[11264 + idx] = *(const uint4*)o;
  }
}

// ---------------- shared QKV MFMA body ----------------
// Qh[N][128] fp16 stored PERMUTED: pos = (ct>>2)*64 + lc*4 + (ct&3) for col ct*16+lc.
// KVf8[N][256] bytes: [0,128) K-plane, [128,256) V-plane; byte p holds col cp(p).
__device__ inline void qkv_mfma(f16x8 af0, f16x8 af1, const uint4* __restrict__ Bq,
                                const uint4* __restrict__ Bk,
                                const uint4* __restrict__ Bv,
                                unsigned short* __restrict__ Qh,
                                unsigned char* __restrict__ KVf8, int nb, int n,
                                int lc, int lg) {
  // Q (fp16 out, permuted positions)
  {
    f32x4 acc[8] = {};
#pragma unroll
    for (int ct = 0; ct < 8; ++ct) {
      acc[ct] = __builtin_amdgcn_mfma_f32_16x16x32_f16(
          af0, bcf16x8(Bq[(ct * 2 + 0) * 64 + lg * 16 + lc]), acc[ct], 0, 0, 0);
      acc[ct] = __builtin_amdgcn_mfma_f32_16x16x32_f16(
          af1, bcf16x8(Bq[(ct * 2 + 1) * 64 + lg * 16 + lc]), acc[ct], 0, 0, 0);
    }
#pragma unroll
    for (int ct = 0; ct < 8; ++ct) {
      int pos = (ct >> 2) * 64 + lc * 4 + (ct & 3);
#pragma unroll
      for (int r = 0; r < 4; ++r) {
        int gn = nb + lg * 4 + r;
        if (gn < n) Qh[(size_t)gn * 128 + pos] = f2h(acc[ct][r]);
      }
    }
  }
  // K,V planes: per head, 4 ct-columns packed into one uint (4 fp8 bytes)
#pragma unroll
  for (int head = 0; head < 2; ++head) {
    f32x4 ka[4], va[4];
#pragma unroll
    for (int c4 = 0; c4 < 4; ++c4) {
      int ct = head * 4 + c4;
      f32x4 kz = {}, vz = {};
      kz = __builtin_amdgcn_mfma_f32_16x16x32_f16(
          af0, bcf16x8(Bk[(ct * 2 + 0) * 64 + lg * 16 + lc]), kz, 0, 0, 0);
      kz = __builtin_amdgcn_mfma_f32_16x16x32_f16(
          af1, bcf16x8(Bk[(ct * 2 + 1) * 64 + lg * 16 + lc]), kz, 0, 0, 0);
      vz = __builtin_amdgcn_mfma_f32_16x16x32_f16(
          af0, bcf16x8(Bv[(ct * 2 + 0) * 64 + lg * 16 + lc]), vz, 0, 0, 0);
      vz = __builtin_amdgcn_mfma_f32_16x16x32_f16(
          af1, bcf16x8(Bv[(ct * 2 + 1) * 64 + lg * 16 + lc]), vz, 0, 0, 0);
      ka[c4] = kz;
      va[c4] = vz;
    }
#pragma unroll
    for (int r = 0; r < 4; ++r) {
      int kw = __builtin_amdgcn_cvt_pk_fp8_f32(ka[0][r], ka[1][r], 0, false);
      kw = __builtin_amdgcn_cvt_pk_fp8_f32(ka[2][r], ka[3][r], kw, true);
      int vw = __builtin_amdgcn_cvt_pk_fp8_f32(va[0][r], va[1][r], 0, false);
      vw = __builtin_amdgcn_cvt_pk_fp8_f32(va[2][r], va[3][r], vw, true);
      int gn = nb + lg * 4 + r;
      if (gn < n) {
        *(unsigned int*)(KVf8 + (size_t)gn * 256 + head * 64 + lc * 4) =
            (unsigned int)kw;
        *(unsigned int*)(KVf8 + (size_t)gn * 256 + 128 + head * 64 + lc * 4) =
            (unsigned int)vw;
      }
    }
  }
}

// ---------------- fused embedding + layer-0 QKV (MFMA, 16-node tile/wave) --------
__global__ __launch_bounds__(256) void k_embqkv(
    const float* __restrict__ x, const uint4* __restrict__ Bemb,
    const float* __restrict__ emb_b, float* __restrict__ h,
    const uint4* __restrict__ Bq, const uint4* __restrict__ Bk,
    const uint4* __restrict__ Bv, unsigned short* __restrict__ Qh,
    unsigned char* __restrict__ KVf8, int n) {
  __shared__ unsigned short red[4][16 * 88];
  int lane = threadIdx.x & 63, wv = threadIdx.x >> 6;
  int nb = (blockIdx.x * 4 + wv) * 16;
  if (nb >= n) return;
  int lc = lane & 15, lg = lane >> 4;

  int arow = (nb + lc < n) ? nb + lc : n - 1;
  const float* xr = x + (size_t)arow * 128;
  f16x8 ax[4];
#pragma unroll
  for (int kk = 0; kk < 4; ++kk) {
    float4 a = *(const float4*)(xr + kk * 32 + lg * 8);
    float4 b = *(const float4*)(xr + kk * 32 + lg * 8 + 4);
    unsigned short o[8] = {f2h(a.x), f2h(a.y), f2h(a.z), f2h(a.w),
                           f2h(b.x), f2h(b.y), f2h(b.z), f2h(b.w)};
    ax[kk] = bcf16x8(*(const uint4*)o);
  }
  f32x4 acc[4] = {};
#pragma unroll
  for (int kk = 0; kk < 4; ++kk)
#pragma unroll
    for (int ct = 0; ct < 4; ++ct)
      acc[ct] = __builtin_amdgcn_mfma_f32_16x16x32_f16(
          ax[kk], bcf16x8(Bemb[(ct * 4 + kk) * 64 + lane]), acc[ct], 0, 0, 0);
#pragma unroll
  for (int ct = 0; ct < 4; ++ct) {
    float bo = emb_b[ct * 16 + lc];
#pragma unroll
    for (int r = 0; r < 4; ++r) {
      float v = acc[ct][r] + bo;
      int gn = nb + lg * 4 + r;
      if (gn < n) h[(size_t)gn * 64 + ct * 16 + lc] = v;
      red[wv][(lg * 4 + r) * 88 + ct * 16 + lc] = f2h(v);
    }
  }
  f16x8 af0 = bcf16x8(*(const uint4*)&red[wv][lc * 88 + lg * 8]);
  f16x8 af1 = bcf16x8(*(const uint4*)&red[wv][lc * 88 + 32 + lg * 8]);
  qkv_mfma(af0, af1, Bq, Bk, Bv, Qh, KVf8, nb, n, lc, lg);
}

// ---------------- attention gather+softmax (fp8 planes, packed-f32 math) ---------
__global__ __launch_bounds__(256) void k_attn(
    const unsigned short* __restrict__ Qh, const unsigned char* __restrict__ KVf8,
    const int* __restrict__ row, const int* __restrict__ srcs,
    unsigned short* __restrict__ aggrh, int n) {
  int lane = threadIdx.x & 63;
  int w = threadIdx.x >> 6;
  int node = blockIdx.x * 4 + w;
  if (node >= n) return;  // no barriers in this kernel
  int sl = lane & 15, gi = lane >> 4;

  // q pairs (f32x2) for byte positions sl*8..+7 (pre-scaled by 1/8*log2e)
  uint4 qr = *(const uint4*)(Qh + (size_t)node * 128 + sl * 8);
  h2 qh0 = bch2(qr.x), qh1 = bch2(qr.y), qh2 = bch2(qr.z), qh3 = bch2(qr.w);
  f32x2 q01 = {(float)qh0[0], (float)qh0[1]};
  f32x2 q23 = {(float)qh1[0], (float)qh1[1]};
  f32x2 q45 = {(float)qh2[0], (float)qh2[1]};
  f32x2 q67 = {(float)qh3[0], (float)qh3[1]};

  int rs = row[node], re = row[node + 1];
  int deg = re - rs;
  float den = 0.f;
  f32x2 av0 = {0, 0}, av1 = {0, 0}, av2 = {0, 0}, av3 = {0, 0};

  if (deg > 0) {
    int iters = (deg + 3) >> 2;
    uint2 Kb[4], Vb[4];
    int sxb[4];
#pragma unroll
    for (int s = 0; s < 4; ++s) {
      if (s < iters) {
        int ei = rs + s * 4 + gi;
        int sx = (ei < re) ? srcs[ei] : srcs[rs];
        const unsigned char* rp = KVf8 + (size_t)sx * 256;
        Kb[s] = *(const uint2*)(rp + sl * 8);
        Vb[s] = *(const uint2*)(rp + 128 + sl * 8);
      }
      int ei2 = rs + (s + 4) * 4 + gi;
      sxb[s] = (ei2 < re) ? srcs[ei2] : srcs[rs];
    }
    for (int it = 0; it < iters; it += 4) {
#pragma unroll
      for (int s = 0; s < 4; ++s) {
        int cit = it + s;
        if (cit < iters) {  // wave-uniform
          uint2 Kd = Kb[s], Vd = Vb[s];
          if (cit + 4 < iters) {
            const unsigned char* rp = KVf8 + (size_t)sxb[s] * 256;
            Kb[s] = *(const uint2*)(rp + sl * 8);
            Vb[s] = *(const uint2*)(rp + 128 + sl * 8);
          }
          {
            int ei3 = rs + (cit + 8) * 4 + gi;
            sxb[s] = (ei3 < re) ? srcs[ei3] : srcs[rs];
          }
          // packed score: 4 x v_pk_fma_f32
          f32x2 s2 = __builtin_amdgcn_cvt_pk_f32_fp8(Kd.x, false) * q01;
          s2 += __builtin_amdgcn_cvt_pk_f32_fp8(Kd.x, true) * q23;
          s2 += __builtin_amdgcn_cvt_pk_f32_fp8(Kd.y, false) * q45;
          s2 += __builtin_amdgcn_cvt_pk_f32_fp8(Kd.y, true) * q67;
          float sc = s2.x + s2.y;
          sc += __shfl_xor(sc, 1, 64);
          sc += __shfl_xor(sc, 2, 64);
          sc += __shfl_xor(sc, 4, 64);  // octet-sum: head (sl>>3) score of edge gi
          bool ev = (rs + cit * 4 + gi) < re;
          float wgt = ev ? __builtin_amdgcn_exp2f(sc) : 0.f;
          den += wgt;
          f32x2 w2 = {wgt, wgt};
          av0 += w2 * __builtin_amdgcn_cvt_pk_f32_fp8(Vd.x, false);
          av1 += w2 * __builtin_amdgcn_cvt_pk_f32_fp8(Vd.x, true);
          av2 += w2 * __builtin_amdgcn_cvt_pk_f32_fp8(Vd.y, false);
          av3 += w2 * __builtin_amdgcn_cvt_pk_f32_fp8(Vd.y, true);
        }
      }
    }
  }
  // combine 4 edge groups
#pragma unroll
  for (int d = 16; d < 64; d <<= 1) {
    den += __shfl_xor(den, d, 64);
    av0.x += __shfl_xor(av0.x, d, 64);
    av0.y += __shfl_xor(av0.y, d, 64);
    av1.x += __shfl_xor(av1.x, d, 64);
    av1.y += __shfl_xor(av1.y, d, 64);
    av2.x += __shfl_xor(av2.x, d, 64);
    av2.y += __shfl_xor(av2.y, d, 64);
    av3.x += __shfl_xor(av3.x, d, 64);
    av3.y += __shfl_xor(av3.y, d, 64);
  }
  float inv = fminf(1.f / (den + 1e-16f), 60000.f);
  if (lane < 16) {
    uint4 o;
    o.x = pkrtz(av0.x * inv, av0.y * inv);
    o.y = pkrtz(av1.x * inv, av1.y * inv);
    o.z = pkrtz(av2.x * inv, av2.y * inv);
    o.w = pkrtz(av3.x * inv, av3.y * inv);
    *(uint4*)(aggrh + (size_t)node * 128 + sl * 8) = o;  // permuted positions
  }
}

// ---------------- post (MFMA): Wout -> +res -> LN -> FFN, then:
// MODE 0: next-layer QKV.  MODE 1: logits + log_softmax.
template <int MODE>
__global__ __launch_bounds__(256) void k_post(
    const unsigned short* __restrict__ aggrh, float* __restrict__ h,
    const uint4* __restrict__ Bout, const float* __restrict__ bout,
    const float* __restrict__ lng, const float* __restrict__ lnb,
    const uint4* __restrict__ B1, const float* __restrict__ b1,
    const uint4* __restrict__ B2, const float* __restrict__ b2,
    const uint4* __restrict__ BqN, const uint4* __restrict__ BkN,
    const uint4* __restrict__ BvN, unsigned short* __restrict__ Qh,
    unsigned char* __restrict__ KVf8,
    const uint4* __restrict__ Bo, const float* __restrict__ out_b,
    float* __restrict__ out, int n) {
  __shared__ unsigned short red[4][16 * 88];
  int lane = threadIdx.x & 63, wv = threadIdx.x >> 6;
  int nb = (blockIdx.x * 4 + wv) * 16;
  if (nb >= n) return;  // no barriers in this kernel
  int lc = lane & 15, lg = lane >> 4;

  // GEMM1: O = aggr(permuted) @ Bout(colperm'd)
  f32x4 acc[4] = {};
  const uint4* arow_p = (const uint4*)(aggrh + (size_t)(nb + lc) * 128);
#pragma unroll
  for (int kk = 0; kk < 4; ++kk) {
    f16x8 af = bcf16x8(arow_p[kk * 4 + lg]);
#pragma unroll
    for (int ct = 0; ct < 4; ++ct)
      acc[ct] = __builtin_amdgcn_mfma_f32_16x16x32_f16(
          af, bcf16x8(Bout[(ct * 4 + kk) * 64 + lane]), acc[ct], 0, 0, 0);
  }

  // bias + residual + layernorm
  float x[4][4], hl[4][4];
#pragma unroll
  for (int ct = 0; ct < 4; ++ct) {
    float bo = bout[ct * 16 + lc];
#pragma unroll
    for (int r = 0; r < 4; ++r)
      x[r][ct] = acc[ct][r] + bo + h[(size_t)(nb + lg * 4 + r) * 64 + ct * 16 + lc];
  }
  float g[4], bb[4];
#pragma unroll
  for (int ct = 0; ct < 4; ++ct) {
    g[ct] = lng[ct * 16 + lc];
    bb[ct] = lnb[ct * 16 + lc];
  }
#pragma unroll
  for (int r = 0; r < 4; ++r) {
    float s = x[r][0] + x[r][1] + x[r][2] + x[r][3];
    s += __shfl_xor(s, 1, 64);
    s += __shfl_xor(s, 2, 64);
    s += __shfl_xor(s, 4, 64);
    s += __shfl_xor(s, 8, 64);
    float mu = s * (1.f / 64.f);
    float s2 = 0.f;
#pragma unroll
    for (int ct = 0; ct < 4; ++ct) {
      float xc = x[r][ct] - mu;
      s2 += xc * xc;
    }
    s2 += __shfl_xor(s2, 1, 64);
    s2 += __shfl_xor(s2, 2, 64);
    s2 += __shfl_xor(s2, 4, 64);
    s2 += __shfl_xor(s2, 8, 64);
    float inv = rsqrtf(s2 * (1.f / 64.f) + 1e-5f);
#pragma unroll
    for (int ct = 0; ct < 4; ++ct) {
      hl[r][ct] = (x[r][ct] - mu) * inv * g[ct] + bb[ct];
      red[wv][(lg * 4 + r) * 88 + ct * 16 + lc] = f2h(hl[r][ct]);
    }
  }

  // GEMM2: T = relu(hl @ W1 + b1)
  f32x4 acc2[4] = {};
#pragma unroll
  for (int kk = 0; kk < 2; ++kk) {
    f16x8 af = bcf16x8(*(const uint4*)&red[wv][lc * 88 + kk * 32 + lg * 8]);
#pragma unroll
    for (int ct = 0; ct < 4; ++ct)
      acc2[ct] = __builtin_amdgcn_mfma_f32_16x16x32_f16(
          af, bcf16x8(B1[(ct * 2 + kk) * 64 + lane]), acc2[ct], 0, 0, 0);
  }
#pragma unroll
  for (int ct = 0; ct < 4; ++ct) {
    float b1c = b1[ct * 16 + lc];
#pragma unroll
    for (int r = 0; r < 4; ++r)
      red[wv][(lg * 4 + r) * 88 + ct * 16 + lc] = f2h(fmaxf(acc2[ct][r] + b1c, 0.f));
  }

  // GEMM3: hfin = hl + T @ W2 + b2
  f32x4 acc3[4] = {};
#pragma unroll
  for (int kk = 0; kk < 2; ++kk) {
    f16x8 af = bcf16x8(*(const uint4*)&red[wv][lc * 88 + kk * 32 + lg * 8]);
#pragma unroll
    for (int ct = 0; ct < 4; ++ct)
      acc3[ct] = __builtin_amdgcn_mfma_f32_16x16x32_f16(
          af, bcf16x8(B2[(ct * 2 + kk) * 64 + lane]), acc3[ct], 0, 0, 0);
  }
#pragma unroll
  for (int ct = 0; ct < 4; ++ct) {
    float b2c = b2[ct * 16 + lc];
#pragma unroll
    for (int r = 0; r < 4; ++r) {
      float v = hl[r][ct] + acc3[ct][r] + b2c;
      int gn = nb + lg * 4 + r;
      if (MODE == 0 && gn < n) h[(size_t)gn * 64 + ct * 16 + lc] = v;
      red[wv][(lg * 4 + r) * 88 + ct * 16 + lc] = f2h(v);
    }
  }

  if (MODE == 0) {
    f16x8 af0 = bcf16x8(*(const uint4*)&red[wv][lc * 88 + lg * 8]);
    f16x8 af1 = bcf16x8(*(const uint4*)&red[wv][lc * 88 + 32 + lg * 8]);
    qkv_mfma(af0, af1, BqN, BkN, BvN, Qh, KVf8, nb, n, lc, lg);
  } else {
    f32x4 lg4[3] = {};
#pragma unroll
    for (int kk = 0; kk < 2; ++kk) {
      f16x8 af = bcf16x8(*(const uint4*)&red[wv][lc * 88 + kk * 32 + lg * 8]);
#pragma unroll
      for (int ct = 0; ct < 3; ++ct)
        lg4[ct] = __builtin_amdgcn_mfma_f32_16x16x32_f16(
            af, bcf16x8(Bo[(ct * 2 + kk) * 64 + lane]), lg4[ct], 0, 0, 0);
    }
    float ob0 = out_b[lc], ob1 = out_b[16 + lc];
    float ob2 = (lc < 8) ? out_b[32 + lc] : 0.f;
#pragma unroll
    for (int r = 0; r < 4; ++r) {
      float l0 = lg4[0][r] + ob0;
      float l1 = lg4[1][r] + ob1;
      float l2 = (lc < 8) ? (lg4[2][r] + ob2) : -3.0e38f;
      float m = fmaxf(fmaxf(l0, l1), l2);
      m = fmaxf(m, __shfl_xor(m, 1, 64));
      m = fmaxf(m, __shfl_xor(m, 2, 64));
      m = fmaxf(m, __shfl_xor(m, 4, 64));
      m = fmaxf(m, __shfl_xor(m, 8, 64));
      float e = __expf(l0 - m) + __expf(l1 - m) + ((lc < 8) ? __expf(l2 - m) : 0.f);
      e += __shfl_xor(e, 1, 64);
      e += __shfl_xor(e, 2, 64);
      e += __shfl_xor(e, 4, 64);
      e += __shfl_xor(e, 8, 64);
      float ls = m + logf(e);
      int gn = nb + lg * 4 + r;
      if (gn < n) {
        out[(size_t)gn * 40 + lc] = l0 - ls;
        out[(size_t)gn * 40 + 16 + lc] = l1 - ls;
        if (lc < 8) out[(size_t)gn * 40 + 32 + lc] = l2 - ls;
      }
    }
  }
}

extern "C" void kernel_launch(void* const* d_in, const int* in_sizes, int n_in,
                              void* d_out, int out_size, void* d_ws, size_t ws_size,
                              hipStream_t stream) {
  const float* x     = (const float*)d_in[0];
  const int*   ei    = (const int*)d_in[1];
  const float* emb_w = (const float*)d_in[2];
  const float* emb_b = (const float*)d_in[3];
  const float* Wq    = (const float*)d_in[4];   // [2,64,128]
  const float* Wk    = (const float*)d_in[5];
  const float* Wv    = (const float*)d_in[6];
  const float* Wout  = (const float*)d_in[7];   // [2,128,64]
  const float* bout  = (const float*)d_in[8];
  const float* ln_g  = (const float*)d_in[9];
  const float* ln_b  = (const float*)d_in[10];
  const float* W1    = (const float*)d_in[11];  // [2,64,64]
  const float* b1    = (const float*)d_in[12];
  const float* W2    = (const float*)d_in[13];
  const float* b2    = (const float*)d_in[14];
  const float* out_w = (const float*)d_in[15];  // [64,40]
  const float* out_b = (const float*)d_in[16];
  float* out = (float*)d_out;

  const int n = in_sizes[0] / DIN;  // 50000
  const int E = in_sizes[1] / 2;    // 800000

  char* ws = (char*)d_ws;
  size_t off = 0;
  auto alloc = [&](size_t bytes) {
    void* p = ws + off;
    off = (off + bytes + 255) & ~(size_t)255;
    return p;
  };
  float* h              = (float*)alloc((size_t)n * 64 * 4);
  unsigned short* Qh    = (unsigned short*)alloc((size_t)n * 128 * 2);
  unsigned char* KVf8   = (unsigned char*)alloc((size_t)n * 256);
  unsigned short* aggrh = (unsigned short*)alloc((size_t)n * 128 * 2);
  int* rowp             = (int*)alloc((size_t)(n + 1) * 4);
  int* srcs             = (int*)alloc((size_t)E * 4);
  uint4* WP             = (uint4*)alloc((size_t)11648 * 16);
  int nblkA             = (E + 4095) / 4096;
  int nbkt              = (n + 127) >> BKTSH;
  int* bhist2           = (int*)alloc((size_t)NBKTCAP * nblkA * 4);
  int* btot             = (int*)alloc((size_t)NBKTCAP * 4);
  int* bktBase          = (int*)alloc((size_t)(NBKTCAP + 1) * 4);
  int2* ebuf            = (int2*)alloc((size_t)E * 8);

  const int* src = ei;
  const int* dst = ei + E;

  // CSR build via 2-level bucket sort
  k_bktA<<<nblkA, 256, 0, stream>>>(dst, bhist2, nblkA, E, nbkt);
  k_bktScan1<<<(nbkt + 3) / 4, 256, 0, stream>>>(bhist2, btot, nblkA, nbkt);
  k_bktScan2<<<1, 512, 0, stream>>>(btot, bktBase, rowp, nbkt, E, n);
  k_bktB<<<nblkA, 256, 0, stream>>>(src, dst, bhist2, bktBase, ebuf, nblkA, E, nbkt);
  k_bktC<<<nbkt, 256, 0, stream>>>(ebuf, bktBase, rowp, srcs, n);

  k_wpack<<<40, 256, 0, stream>>>(Wq, Wk, Wv, Wout, W1, W2, WP);
  k_wpack2<<<6, 256, 0, stream>>>(emb_w, out_w, WP);

  const uint4* L0 = WP;
  const uint4* L1 = WP + 5120;
  const uint4* Bemb = WP + 10240;
  const uint4* Bo = WP + 11264;

  // embedding + layer-0 QKV fused
  k_embqkv<<<(n + 63) / 64, 256, 0, stream>>>(x, Bemb, emb_b, h, L0, L0 + 1024,
                                              L0 + 2048, Qh, KVf8, n);

  // layer 0: attn -> post(+layer-1 QKV)
  k_attn<<<(n + 3) / 4, 256, 0, stream>>>(Qh, KVf8, rowp, srcs, aggrh, n);
  k_post<0><<<(n + 63) / 64, 256, 0, stream>>>(
      aggrh, h, L0 + 3072, bout, ln_g, ln_b, L0 + 4096, b1, L0 + 4608, b2,
      L1, L1 + 1024, L1 + 2048, Qh, KVf8, nullptr, nullptr, nullptr, n);

  // layer 1: attn -> post(+logits/log_softmax)
  k_attn<<<(n + 3) / 4, 256, 0, stream>>>(Qh, KVf8, rowp, srcs, aggrh, n);
  k_post<1><<<(n + 63) / 64, 256, 0, stream>>>(
      aggrh, h, L1 + 3072, bout + 64, ln_g + 64, ln_b + 64, L1 + 4096, b1 + 64,
      L1 + 4608, b2 + 64, nullptr, nullptr, nullptr, nullptr, nullptr,
      Bo, out_b, out, n);
}

// Round 17
// 182.845 us; speedup vs baseline: 1.7444x; 1.0184x over previous
//
#include <hip/hip_runtime.h>
#include <math.h>

#define DIN 128
#define HID 64
#define BKTSH 7      // 128 nodes per coarse bucket
#define NBKTCAP 512  // max buckets (n <= 65536; src packed in 16 bits needs n <= 65536)
#define CAPC 2560    // max edges per bucket for LDS fast path

typedef _Float16 h2 __attribute__((ext_vector_type(2)));
typedef _Float16 f16x8 __attribute__((ext_vector_type(8)));
typedef float f32x4 __attribute__((ext_vector_type(4)));
typedef float f32x2 __attribute__((ext_vector_type(2)));

__device__ inline unsigned short f2h(float f) {
  return __builtin_bit_cast(unsigned short, (_Float16)f);
}
__device__ inline h2 bch2(unsigned int u) { return __builtin_bit_cast(h2, u); }
__device__ inline unsigned int pkrtz(float a, float b) {
  return __builtin_bit_cast(unsigned int, __builtin_amdgcn_cvt_pkrtz(a, b));
}
__device__ inline f16x8 bcf16x8(uint4 u) { return __builtin_bit_cast(f16x8, u); }

// ---------------- CSR build: 2-level bucket sort ----------------
// r13: random 4B global scatters cost 64B/line. r14: no serial one-block scans.
// r16: edge records packed to 4B (src:16 | local:7) — halves pass-B/C traffic.

__global__ __launch_bounds__(256) void k_bktA(const int* __restrict__ dst,
                                              int* __restrict__ bhist,
                                              int nblkA, int E, int nbkt) {
  __shared__ int hist[NBKTCAP];
  int tid = threadIdx.x;
  for (int i = tid; i < nbkt; i += 256) hist[i] = 0;
  __syncthreads();
#pragma unroll
  for (int i = 0; i < 16; ++i) {
    int e = blockIdx.x * 4096 + i * 256 + tid;
    if (e < E) atomicAdd(&hist[dst[e] >> BKTSH], 1);
  }
  __syncthreads();
  for (int i = tid; i < nbkt; i += 256) bhist[i * nblkA + blockIdx.x] = hist[i];
}

__global__ __launch_bounds__(256) void k_bktScan1(int* __restrict__ bhist,
                                                  int* __restrict__ btot,
                                                  int nblkA, int nbkt) {
  int wv = threadIdx.x >> 6, lane = threadIdx.x & 63;
  int b = blockIdx.x * 4 + wv;
  if (b >= nbkt) return;
  int* rowp = bhist + (size_t)b * nblkA;
  int carry = 0;
  for (int base = 0; base < nblkA; base += 64) {
    int i = base + lane;
    int v = (i < nblkA) ? rowp[i] : 0;
    int incl = v;
#pragma unroll
    for (int d = 1; d < 64; d <<= 1) {
      int t = __shfl_up(incl, d, 64);
      if (lane >= d) incl += t;
    }
    if (i < nblkA) rowp[i] = carry + incl - v;
    carry += __shfl(incl, 63, 64);
  }
  if (lane == 0) btot[b] = carry;
}

__global__ __launch_bounds__(512) void k_bktScan2(const int* __restrict__ btot,
                                                  int* __restrict__ bktBase,
                                                  int* __restrict__ rowp,
                                                  int nbkt, int E, int n) {
  __shared__ int sc[512];
  int b = threadIdx.x;
  int s = (b < nbkt) ? btot[b] : 0;
  sc[b] = s;
  __syncthreads();
  for (int d = 1; d < 512; d <<= 1) {
    int v = (b >= d) ? sc[b - d] : 0;
    __syncthreads();
    sc[b] += v;
    __syncthreads();
  }
  if (b < nbkt) bktBase[b] = sc[b] - s;
  if (b == 0) {
    bktBase[nbkt] = E;
    rowp[n] = E;
  }
}

__global__ __launch_bounds__(256) void k_bktB(const int* __restrict__ src,
                                              const int* __restrict__ dst,
                                              const int* __restrict__ bpos,
                                              const int* __restrict__ bktBase,
                                              unsigned int* __restrict__ ebuf,
                                              int nblkA, int E, int nbkt) {
  __shared__ int cur[NBKTCAP];
  int tid = threadIdx.x;
  for (int i = tid; i < nbkt; i += 256)
    cur[i] = bpos[i * nblkA + blockIdx.x] + bktBase[i];
  __syncthreads();
#pragma unroll
  for (int i = 0; i < 16; ++i) {
    int e = blockIdx.x * 4096 + i * 256 + tid;
    if (e < E) {
      int d = dst[e];
      int pos = atomicAdd(&cur[d >> BKTSH], 1);
      ebuf[pos] = (unsigned int)src[e] | ((unsigned int)(d & 127) << 16);
    }
  }
}

__global__ __launch_bounds__(256) void k_bktC(const unsigned int* __restrict__ ebuf,
                                              const int* __restrict__ bktBase,
                                              int* __restrict__ rowp,
                                              int* __restrict__ srcs, int n) {
  __shared__ unsigned int rec[CAPC];
  __shared__ int outv[CAPC];
  __shared__ int hist[128];
  __shared__ int sc[128];
  __shared__ int cur2[128];
  int b = blockIdx.x;
  int tid = threadIdx.x;
  int s0 = bktBase[b], s1 = bktBase[b + 1];
  int cnt = s1 - s0;
  int nodeBase = b << BKTSH;
  if (tid < 128) hist[tid] = 0;
  __syncthreads();
  bool fast = (cnt <= CAPC);
  if (fast) {
    for (int i = tid; i < cnt; i += 256) {
      unsigned int r = ebuf[s0 + i];
      rec[i] = r;
      atomicAdd(&hist[r >> 16], 1);
    }
  } else {
    for (int i = tid; i < cnt; i += 256) atomicAdd(&hist[ebuf[s0 + i] >> 16], 1);
  }
  __syncthreads();
  if (tid < 128) sc[tid] = hist[tid];
  __syncthreads();
  for (int d = 1; d < 128; d <<= 1) {
    int v = (tid < 128 && tid >= d) ? sc[tid - d] : 0;
    __syncthreads();
    if (tid < 128) sc[tid] += v;
    __syncthreads();
  }
  if (tid < 128) {
    int excl = sc[tid] - hist[tid];
    int node = nodeBase + tid;
    if (node < n) rowp[node] = s0 + excl;
    cur2[tid] = excl;
  }
  __syncthreads();
  if (fast) {
    for (int i = tid; i < cnt; i += 256) {
      unsigned int r = rec[i];
      int pos = atomicAdd(&cur2[r >> 16], 1);
      outv[pos] = (int)(r & 0xFFFFu);
    }
    __syncthreads();
    for (int i = tid; i < cnt; i += 256) srcs[s0 + i] = outv[i];
  } else {
    for (int i = tid; i < cnt; i += 256) {
      unsigned int r = ebuf[s0 + i];
      int pos = atomicAdd(&cur2[r >> 16], 1);
      srcs[s0 + pos] = (int)(r & 0xFFFFu);
    }
  }
}

// ---------------- weight pre-pack: fp32 -> fp16 B-fragments ----------------
// WP layout (uint4) per layer l at l*5120: [0,1024) Bq(x0.125*log2e), [1024,2048) Bk,
// [2048,3072) Bv, [3072,4096) Bout (colperm'd k-map), [4096,4608) B1, [4608,5120) B2.
__global__ __launch_bounds__(256) void k_wpack(
    const float* __restrict__ Wq, const float* __restrict__ Wk,
    const float* __restrict__ Wv, const float* __restrict__ Wout,
    const float* __restrict__ W1, const float* __restrict__ W2,
    uint4* __restrict__ P) {
  int t = blockIdx.x * 256 + threadIdx.x;  // 0..10239
  if (t >= 10240) return;
  int layer = t / 5120;
  int r = t - layer * 5120;
  const float* W;
  int idx, nkk, ld, base;
  float scale = 1.f;
  bool permk = false;
  if (r < 1024) {
    W = Wq + layer * 64 * 128; idx = r; nkk = 2; ld = 128;
    scale = 0.125f * 1.44269504089f; base = 0;
  } else if (r < 2048) {
    W = Wk + layer * 64 * 128; idx = r - 1024; nkk = 2; ld = 128; base = 1024;
  } else if (r < 3072) {
    W = Wv + layer * 64 * 128; idx = r - 2048; nkk = 2; ld = 128; base = 2048;
  } else if (r < 4096) {
    W = Wout + layer * 128 * 64; idx = r - 3072; nkk = 4; ld = 64; base = 3072;
    permk = true;
  } else if (r < 4608) {
    W = W1 + layer * 64 * 64; idx = r - 4096; nkk = 2; ld = 64; base = 4096;
  } else {
    W = W2 + layer * 64 * 64; idx = r - 4608; nkk = 2; ld = 64; base = 4608;
  }
  int lane = idx & 63;
  int g = idx >> 6;
  int ct = g / nkk, kk = g - ct * nkk;
  int lc = lane & 15, lg = lane >> 4;
  unsigned short o[8];
#pragma unroll
  for (int i = 0; i < 8; ++i) {
    int rr = kk * 32 + lg * 8 + i;
    if (permk) {
      int bb = rr & 63;
      rr = (rr & 64) + (bb & 3) * 16 + (bb >> 2);
    }
    o[i] = f2h(W[rr * ld + ct * 16 + lc] * scale);
  }
  P[layer * 5120 + base + idx] = *(const uint4*)o;
}

// Bemb at WP[10240,11264); Bo at WP[11264,11648) (ld=40, zero-padded cols>=40).
__global__ __launch_bounds__(256) void k_wpack2(const float* __restrict__ emb_w,
                                                const float* __restrict__ out_w,
                                                uint4* __restrict__ P) {
  int t = blockIdx.x * 256 + threadIdx.x;  // 0..1407
  if (t >= 1408) return;
  int lane, ct, kk, lc, lg;
  unsigned short o[8];
  if (t < 1024) {
    int idx = t;
    lane = idx & 63;
    int g = idx >> 6;
    ct = g >> 2; kk = g & 3;
    lc = lane & 15; lg = lane >> 4;
#pragma unroll
    for (int i = 0; i < 8; ++i)
      o[i] = f2h(emb_w[(kk * 32 + lg * 8 + i) * 64 + ct * 16 + lc]);
    P[10240 + idx] = *(const uint4*)o;
  } else {
    int idx = t - 1024;
    lane = idx & 63;
    int g = idx >> 6;
    ct = g >> 1; kk = g & 1;
    lc = lane & 15; lg = lane >> 4;
    int col = ct * 16 + lc;
#pragma unroll
    for (int i = 0; i < 8; ++i)
      o[i] = (col < 40) ? f2h(out_w[(kk * 32 + lg * 8 + i) * 40 + col]) : (unsigned short)0;
    P[11264 + idx] = *(const uint4*)o;
  }
}

// ---------------- shared QKV MFMA body ----------------
// Qh[N][128] fp16 PERMUTED: pos = (ct>>2)*64 + lc*4 + (ct&3) for col ct*16+lc.
// KVf8[N][256] bytes interleaved in 16B groups: group g (g=0..15):
//   bytes [16g,16g+8) = K-plane positions 8g..8g+7, [16g+8,16g+16) = V same positions.
__device__ inline void qkv_mfma(f16x8 af0, f16x8 af1, const uint4* __restrict__ Bq,
                                const uint4* __restrict__ Bk,
                                const uint4* __restrict__ Bv,
                                unsigned short* __restrict__ Qh,
                                unsigned char* __restrict__ KVf8, int nb, int n,
                                int lc, int lg) {
  // Q (fp16 out, permuted positions)
  {
    f32x4 acc[8] = {};
#pragma unroll
    for (int ct = 0; ct < 8; ++ct) {
      acc[ct] = __builtin_amdgcn_mfma_f32_16x16x32_f16(
          af0, bcf16x8(Bq[(ct * 2 + 0) * 64 + lg * 16 + lc]), acc[ct], 0, 0, 0);
      acc[ct] = __builtin_amdgcn_mfma_f32_16x16x32_f16(
          af1, bcf16x8(Bq[(ct * 2 + 1) * 64 + lg * 16 + lc]), acc[ct], 0, 0, 0);
    }
#pragma unroll
    for (int ct = 0; ct < 8; ++ct) {
      int pos = (ct >> 2) * 64 + lc * 4 + (ct & 3);
#pragma unroll
      for (int r = 0; r < 4; ++r) {
        int gn = nb + lg * 4 + r;
        if (gn < n) Qh[(size_t)gn * 128 + pos] = f2h(acc[ct][r]);
      }
    }
  }
  // K,V: per head, 4 ct-columns pack into one 4B word; interleaved group layout.
  // K word for plane position p0 = head*64 + lc*4: addr = (p0>>3)*16 + (p0&7); V same +8.
#pragma unroll
  for (int head = 0; head < 2; ++head) {
    f32x4 ka[4], va[4];
#pragma unroll
    for (int c4 = 0; c4 < 4; ++c4) {
      int ct = head * 4 + c4;
      f32x4 kz = {}, vz = {};
      kz = __builtin_amdgcn_mfma_f32_16x16x32_f16(
          af0, bcf16x8(Bk[(ct * 2 + 0) * 64 + lg * 16 + lc]), kz, 0, 0, 0);
      kz = __builtin_amdgcn_mfma_f32_16x16x32_f16(
          af1, bcf16x8(Bk[(ct * 2 + 1) * 64 + lg * 16 + lc]), kz, 0, 0, 0);
      vz = __builtin_amdgcn_mfma_f32_16x16x32_f16(
          af0, bcf16x8(Bv[(ct * 2 + 0) * 64 + lg * 16 + lc]), vz, 0, 0, 0);
      vz = __builtin_amdgcn_mfma_f32_16x16x32_f16(
          af1, bcf16x8(Bv[(ct * 2 + 1) * 64 + lg * 16 + lc]), vz, 0, 0, 0);
      ka[c4] = kz;
      va[c4] = vz;
    }
    int gaddr = (head * 8 + (lc >> 1)) * 16 + (lc & 1) * 4;
#pragma unroll
    for (int r = 0; r < 4; ++r) {
      int kw = __builtin_amdgcn_cvt_pk_fp8_f32(ka[0][r], ka[1][r], 0, false);
      kw = __builtin_amdgcn_cvt_pk_fp8_f32(ka[2][r], ka[3][r], kw, true);
      int vw = __builtin_amdgcn_cvt_pk_fp8_f32(va[0][r], va[1][r], 0, false);
      vw = __builtin_amdgcn_cvt_pk_fp8_f32(va[2][r], va[3][r], vw, true);
      int gn = nb + lg * 4 + r;
      if (gn < n) {
        *(unsigned int*)(KVf8 + (size_t)gn * 256 + gaddr) = (unsigned int)kw;
        *(unsigned int*)(KVf8 + (size_t)gn * 256 + gaddr + 8) = (unsigned int)vw;
      }
    }
  }
}

// ---------------- fused embedding + layer-0 QKV (MFMA, 16-node tile/wave) --------
__global__ __launch_bounds__(256) void k_embqkv(
    const float* __restrict__ x, const uint4* __restrict__ Bemb,
    const float* __restrict__ emb_b, float* __restrict__ h,
    const uint4* __restrict__ Bq, const uint4* __restrict__ Bk,
    const uint4* __restrict__ Bv, unsigned short* __restrict__ Qh,
    unsigned char* __restrict__ KVf8, int n) {
  __shared__ unsigned short red[4][16 * 88];
  int lane = threadIdx.x & 63, wv = threadIdx.x >> 6;
  int nb = (blockIdx.x * 4 + wv) * 16;
  if (nb >= n) return;
  int lc = lane & 15, lg = lane >> 4;

  int arow = (nb + lc < n) ? nb + lc : n - 1;
  const float* xr = x + (size_t)arow * 128;
  f16x8 ax[4];
#pragma unroll
  for (int kk = 0; kk < 4; ++kk) {
    float4 a = *(const float4*)(xr + kk * 32 + lg * 8);
    float4 b = *(const float4*)(xr + kk * 32 + lg * 8 + 4);
    unsigned short o[8] = {f2h(a.x), f2h(a.y), f2h(a.z), f2h(a.w),
                           f2h(b.x), f2h(b.y), f2h(b.z), f2h(b.w)};
    ax[kk] = bcf16x8(*(const uint4*)o);
  }
  f32x4 acc[4] = {};
#pragma unroll
  for (int kk = 0; kk < 4; ++kk)
#pragma unroll
    for (int ct = 0; ct < 4; ++ct)
      acc[ct] = __builtin_amdgcn_mfma_f32_16x16x32_f16(
          ax[kk], bcf16x8(Bemb[(ct * 4 + kk) * 64 + lane]), acc[ct], 0, 0, 0);
#pragma unroll
  for (int ct = 0; ct < 4; ++ct) {
    float bo = emb_b[ct * 16 + lc];
#pragma unroll
    for (int r = 0; r < 4; ++r) {
      float v = acc[ct][r] + bo;
      int gn = nb + lg * 4 + r;
      if (gn < n) h[(size_t)gn * 64 + ct * 16 + lc] = v;
      red[wv][(lg * 4 + r) * 88 + ct * 16 + lc] = f2h(v);
    }
  }
  f16x8 af0 = bcf16x8(*(const uint4*)&red[wv][lc * 88 + lg * 8]);
  f16x8 af1 = bcf16x8(*(const uint4*)&red[wv][lc * 88 + 32 + lg * 8]);
  qkv_mfma(af0, af1, Bq, Bk, Bv, Qh, KVf8, nb, n, lc, lg);
}

// ---------------- attention gather+softmax (fp8 interleaved, 1x16B load/edge) ----
__global__ __launch_bounds__(256) void k_attn(
    const unsigned short* __restrict__ Qh, const unsigned char* __restrict__ KVf8,
    const int* __restrict__ row, const int* __restrict__ srcs,
    unsigned short* __restrict__ aggrh, int n) {
  int lane = threadIdx.x & 63;
  int w = threadIdx.x >> 6;
  int node = blockIdx.x * 4 + w;
  if (node >= n) return;  // no barriers in this kernel
  int sl = lane & 15, gi = lane >> 4;

  // q pairs (f32x2) for plane positions sl*8..+7 (pre-scaled by 1/8*log2e)
  uint4 qr = *(const uint4*)(Qh + (size_t)node * 128 + sl * 8);
  h2 qh0 = bch2(qr.x), qh1 = bch2(qr.y), qh2 = bch2(qr.z), qh3 = bch2(qr.w);
  f32x2 q01 = {(float)qh0[0], (float)qh0[1]};
  f32x2 q23 = {(float)qh1[0], (float)qh1[1]};
  f32x2 q45 = {(float)qh2[0], (float)qh2[1]};
  f32x2 q67 = {(float)qh3[0], (float)qh3[1]};

  int rs = row[node], re = row[node + 1];
  int deg = re - rs;
  float den = 0.f;
  f32x2 av0 = {0, 0}, av1 = {0, 0}, av2 = {0, 0}, av3 = {0, 0};

  if (deg > 0) {
    int iters = (deg + 3) >> 2;
    uint4 Kb[4];
    int sxb[4];
#pragma unroll
    for (int s = 0; s < 4; ++s) {
      if (s < iters) {
        int ei = rs + s * 4 + gi;
        int sx = (ei < re) ? srcs[ei] : srcs[rs];
        Kb[s] = *(const uint4*)(KVf8 + (size_t)sx * 256 + sl * 16);
      }
      int ei2 = rs + (s + 4) * 4 + gi;
      sxb[s] = (ei2 < re) ? srcs[ei2] : srcs[rs];
    }
    for (int it = 0; it < iters; it += 4) {
#pragma unroll
      for (int s = 0; s < 4; ++s) {
        int cit = it + s;
        if (cit < iters) {  // wave-uniform
          uint4 D = Kb[s];
          if (cit + 4 < iters) {
            Kb[s] = *(const uint4*)(KVf8 + (size_t)sxb[s] * 256 + sl * 16);
          }
          {
            int ei3 = rs + (cit + 8) * 4 + gi;
            sxb[s] = (ei3 < re) ? srcs[ei3] : srcs[rs];
          }
          // D.x,D.y = 8 K bytes; D.z,D.w = 8 V bytes (same positions)
          f32x2 s2 = __builtin_amdgcn_cvt_pk_f32_fp8(D.x, false) * q01;
          s2 += __builtin_amdgcn_cvt_pk_f32_fp8(D.x, true) * q23;
          s2 += __builtin_amdgcn_cvt_pk_f32_fp8(D.y, false) * q45;
          s2 += __builtin_amdgcn_cvt_pk_f32_fp8(D.y, true) * q67;
          float sc = s2.x + s2.y;
          sc += __shfl_xor(sc, 1, 64);
          sc += __shfl_xor(sc, 2, 64);
          sc += __shfl_xor(sc, 4, 64);  // octet-sum: head (sl>>3) score of edge gi
          bool ev = (rs + cit * 4 + gi) < re;
          float wgt = ev ? __builtin_amdgcn_exp2f(sc) : 0.f;
          den += wgt;
          f32x2 w2 = {wgt, wgt};
          av0 += w2 * __builtin_amdgcn_cvt_pk_f32_fp8(D.z, false);
          av1 += w2 * __builtin_amdgcn_cvt_pk_f32_fp8(D.z, true);
          av2 += w2 * __builtin_amdgcn_cvt_pk_f32_fp8(D.w, false);
          av3 += w2 * __builtin_amdgcn_cvt_pk_f32_fp8(D.w, true);
        }
      }
    }
  }
  // combine 4 edge groups
#pragma unroll
  for (int d = 16; d < 64; d <<= 1) {
    den += __shfl_xor(den, d, 64);
    av0.x += __shfl_xor(av0.x, d, 64);
    av0.y += __shfl_xor(av0.y, d, 64);
    av1.x += __shfl_xor(av1.x, d, 64);
    av1.y += __shfl_xor(av1.y, d, 64);
    av2.x += __shfl_xor(av2.x, d, 64);
    av2.y += __shfl_xor(av2.y, d, 64);
    av3.x += __shfl_xor(av3.x, d, 64);
    av3.y += __shfl_xor(av3.y, d, 64);
  }
  float inv = fminf(1.f / (den + 1e-16f), 60000.f);
  if (lane < 16) {
    uint4 o;
    o.x = pkrtz(av0.x * inv, av0.y * inv);
    o.y = pkrtz(av1.x * inv, av1.y * inv);
    o.z = pkrtz(av2.x * inv, av2.y * inv);
    o.w = pkrtz(av3.x * inv, av3.y * inv);
    *(uint4*)(aggrh + (size_t)node * 128 + sl * 8) = o;  // permuted positions
  }
}

// ---------------- post (MFMA): Wout -> +res -> LN -> FFN, then:
// MODE 0: next-layer QKV.  MODE 1: logits + log_softmax.
template <int MODE>
__global__ __launch_bounds__(256) void k_post(
    const unsigned short* __restrict__ aggrh, float* __restrict__ h,
    const uint4* __restrict__ Bout, const float* __restrict__ bout,
    const float* __restrict__ lng, const float* __restrict__ lnb,
    const uint4* __restrict__ B1, const float* __restrict__ b1,
    const uint4* __restrict__ B2, const float* __restrict__ b2,
    const uint4* __restrict__ BqN, const uint4* __restrict__ BkN,
    const uint4* __restrict__ BvN, unsigned short* __restrict__ Qh,
    unsigned char* __restrict__ KVf8,
    const uint4* __restrict__ Bo, const float* __restrict__ out_b,
    float* __restrict__ out, int n) {
  __shared__ unsigned short red[4][16 * 88];
  int lane = threadIdx.x & 63, wv = threadIdx.x >> 6;
  int nb = (blockIdx.x * 4 + wv) * 16;
  if (nb >= n) return;  // no barriers in this kernel
  int lc = lane & 15, lg = lane >> 4;

  // GEMM1: O = aggr(permuted) @ Bout(colperm'd)
  f32x4 acc[4] = {};
  const uint4* arow_p = (const uint4*)(aggrh + (size_t)(nb + lc) * 128);
#pragma unroll
  for (int kk = 0; kk < 4; ++kk) {
    f16x8 af = bcf16x8(arow_p[kk * 4 + lg]);
#pragma unroll
    for (int ct = 0; ct < 4; ++ct)
      acc[ct] = __builtin_amdgcn_mfma_f32_16x16x32_f16(
          af, bcf16x8(Bout[(ct * 4 + kk) * 64 + lane]), acc[ct], 0, 0, 0);
  }

  // bias + residual + layernorm
  float x[4][4], hl[4][4];
#pragma unroll
  for (int ct = 0; ct < 4; ++ct) {
    float bo = bout[ct * 16 + lc];
#pragma unroll
    for (int r = 0; r < 4; ++r)
      x[r][ct] = acc[ct][r] + bo + h[(size_t)(nb + lg * 4 + r) * 64 + ct * 16 + lc];
  }
  float g[4], bb[4];
#pragma unroll
  for (int ct = 0; ct < 4; ++ct) {
    g[ct] = lng[ct * 16 + lc];
    bb[ct] = lnb[ct * 16 + lc];
  }
#pragma unroll
  for (int r = 0; r < 4; ++r) {
    float s = x[r][0] + x[r][1] + x[r][2] + x[r][3];
    s += __shfl_xor(s, 1, 64);
    s += __shfl_xor(s, 2, 64);
    s += __shfl_xor(s, 4, 64);
    s += __shfl_xor(s, 8, 64);
    float mu = s * (1.f / 64.f);
    float s2 = 0.f;
#pragma unroll
    for (int ct = 0; ct < 4; ++ct) {
      float xc = x[r][ct] - mu;
      s2 += xc * xc;
    }
    s2 += __shfl_xor(s2, 1, 64);
    s2 += __shfl_xor(s2, 2, 64);
    s2 += __shfl_xor(s2, 4, 64);
    s2 += __shfl_xor(s2, 8, 64);
    float inv = rsqrtf(s2 * (1.f / 64.f) + 1e-5f);
#pragma unroll
    for (int ct = 0; ct < 4; ++ct) {
      hl[r][ct] = (x[r][ct] - mu) * inv * g[ct] + bb[ct];
      red[wv][(lg * 4 + r) * 88 + ct * 16 + lc] = f2h(hl[r][ct]);
    }
  }

  // GEMM2: T = relu(hl @ W1 + b1)
  f32x4 acc2[4] = {};
#pragma unroll
  for (int kk = 0; kk < 2; ++kk) {
    f16x8 af = bcf16x8(*(const uint4*)&red[wv][lc * 88 + kk * 32 + lg * 8]);
#pragma unroll
    for (int ct = 0; ct < 4; ++ct)
      acc2[ct] = __builtin_amdgcn_mfma_f32_16x16x32_f16(
          af, bcf16x8(B1[(ct * 2 + kk) * 64 + lane]), acc2[ct], 0, 0, 0);
  }
#pragma unroll
  for (int ct = 0; ct < 4; ++ct) {
    float b1c = b1[ct * 16 + lc];
#pragma unroll
    for (int r = 0; r < 4; ++r)
      red[wv][(lg * 4 + r) * 88 + ct * 16 + lc] = f2h(fmaxf(acc2[ct][r] + b1c, 0.f));
  }

  // GEMM3: hfin = hl + T @ W2 + b2
  f32x4 acc3[4] = {};
#pragma unroll
  for (int kk = 0; kk < 2; ++kk) {
    f16x8 af = bcf16x8(*(const uint4*)&red[wv][lc * 88 + kk * 32 + lg * 8]);
#pragma unroll
    for (int ct = 0; ct < 4; ++ct)
      acc3[ct] = __builtin_amdgcn_mfma_f32_16x16x32_f16(
          af, bcf16x8(B2[(ct * 2 + kk) * 64 + lane]), acc3[ct], 0, 0, 0);
  }
#pragma unroll
  for (int ct = 0; ct < 4; ++ct) {
    float b2c = b2[ct * 16 + lc];
#pragma unroll
    for (int r = 0; r < 4; ++r) {
      float v = hl[r][ct] + acc3[ct][r] + b2c;
      int gn = nb + lg * 4 + r;
      if (MODE == 0 && gn < n) h[(size_t)gn * 64 + ct * 16 + lc] = v;
      red[wv][(lg * 4 + r) * 88 + ct * 16 + lc] = f2h(v);
    }
  }

  if (MODE == 0) {
    f16x8 af0 = bcf16x8(*(const uint4*)&red[wv][lc * 88 + lg * 8]);
    f16x8 af1 = bcf16x8(*(const uint4*)&red[wv][lc * 88 + 32 + lg * 8]);
    qkv_mfma(af0, af1, BqN, BkN, BvN, Qh, KVf8, nb, n, lc, lg);
  } else {
    f32x4 lg4[3] = {};
#pragma unroll
    for (int kk = 0; kk < 2; ++kk) {
      f16x8 af = bcf16x8(*(const uint4*)&red[wv][lc * 88 + kk * 32 + lg * 8]);
#pragma unroll
      for (int ct = 0; ct < 3; ++ct)
        lg4[ct] = __builtin_amdgcn_mfma_f32_16x16x32_f16(
            af, bcf16x8(Bo[(ct * 2 + kk) * 64 + lane]), lg4[ct], 0, 0, 0);
    }
    float ob0 = out_b[lc], ob1 = out_b[16 + lc];
    float ob2 = (lc < 8) ? out_b[32 + lc] : 0.f;
#pragma unroll
    for (int r = 0; r < 4; ++r) {
      float l0 = lg4[0][r] + ob0;
      float l1 = lg4[1][r] + ob1;
      float l2 = (lc < 8) ? (lg4[2][r] + ob2) : -3.0e38f;
      float m = fmaxf(fmaxf(l0, l1), l2);
      m = fmaxf(m, __shfl_xor(m, 1, 64));
      m = fmaxf(m, __shfl_xor(m, 2, 64));
      m = fmaxf(m, __shfl_xor(m, 4, 64));
      m = fmaxf(m, __shfl_xor(m, 8, 64));
      float e = __expf(l0 - m) + __expf(l1 - m) + ((lc < 8) ? __expf(l2 - m) : 0.f);
      e += __shfl_xor(e, 1, 64);
      e += __shfl_xor(e, 2, 64);
      e += __shfl_xor(e, 4, 64);
      e += __shfl_xor(e, 8, 64);
      float ls = m + logf(e);
      int gn = nb + lg * 4 + r;
      if (gn < n) {
        out[(size_t)gn * 40 + lc] = l0 - ls;
        out[(size_t)gn * 40 + 16 + lc] = l1 - ls;
        if (lc < 8) out[(size_t)gn * 40 + 32 + lc] = l2 - ls;
      }
    }
  }
}

extern "C" void kernel_launch(void* const* d_in, const int* in_sizes, int n_in,
                              void* d_out, int out_size, void* d_ws, size_t ws_size,
                              hipStream_t stream) {
  const float* x     = (const float*)d_in[0];
  const int*   ei    = (const int*)d_in[1];
  const float* emb_w = (const float*)d_in[2];
  const float* emb_b = (const float*)d_in[3];
  const float* Wq    = (const float*)d_in[4];   // [2,64,128]
  const float* Wk    = (const float*)d_in[5];
  const float* Wv    = (const float*)d_in[6];
  const float* Wout  = (const float*)d_in[7];   // [2,128,64]
  const float* bout  = (const float*)d_in[8];
  const float* ln_g  = (const float*)d_in[9];
  const float* ln_b  = (const float*)d_in[10];
  const float* W1    = (const float*)d_in[11];  // [2,64,64]
  const float* b1    = (const float*)d_in[12];
  const float* W2    = (const float*)d_in[13];
  const float* b2    = (const float*)d_in[14];
  const float* out_w = (const float*)d_in[15];  // [64,40]
  const float* out_b = (const float*)d_in[16];
  float* out = (float*)d_out;

  const int n = in_sizes[0] / DIN;  // 50000
  const int E = in_sizes[1] / 2;    // 800000

  char* ws = (char*)d_ws;
  size_t off = 0;
  auto alloc = [&](size_t bytes) {
    void* p = ws + off;
    off = (off + bytes + 255) & ~(size_t)255;
    return p;
  };
  float* h              = (float*)alloc((size_t)n * 64 * 4);
  unsigned short* Qh    = (unsigned short*)alloc((size_t)n * 128 * 2);
  unsigned char* KVf8   = (unsigned char*)alloc((size_t)n * 256);
  unsigned short* aggrh = (unsigned short*)alloc((size_t)n * 128 * 2);
  int* rowp             = (int*)alloc((size_t)(n + 1) * 4);
  int* srcs             = (int*)alloc((size_t)E * 4);
  uint4* WP             = (uint4*)alloc((size_t)11648 * 16);
  int nblkA             = (E + 4095) / 4096;
  int nbkt              = (n + 127) >> BKTSH;
  int* bhist2           = (int*)alloc((size_t)NBKTCAP * nblkA * 4);
  int* btot             = (int*)alloc((size_t)NBKTCAP * 4);
  int* bktBase          = (int*)alloc((size_t)(NBKTCAP + 1) * 4);
  unsigned int* ebuf    = (unsigned int*)alloc((size_t)E * 4);

  const int* src = ei;
  const int* dst = ei + E;

  // CSR build via 2-level bucket sort
  k_bktA<<<nblkA, 256, 0, stream>>>(dst, bhist2, nblkA, E, nbkt);
  k_bktScan1<<<(nbkt + 3) / 4, 256, 0, stream>>>(bhist2, btot, nblkA, nbkt);
  k_bktScan2<<<1, 512, 0, stream>>>(btot, bktBase, rowp, nbkt, E, n);
  k_bktB<<<nblkA, 256, 0, stream>>>(src, dst, bhist2, bktBase, ebuf, nblkA, E, nbkt);
  k_bktC<<<nbkt, 256, 0, stream>>>(ebuf, bktBase, rowp, srcs, n);

  k_wpack<<<40, 256, 0, stream>>>(Wq, Wk, Wv, Wout, W1, W2, WP);
  k_wpack2<<<6, 256, 0, stream>>>(emb_w, out_w, WP);

  const uint4* L0 = WP;
  const uint4* L1 = WP + 5120;
  const uint4* Bemb = WP + 10240;
  const uint4* Bo = WP + 11264;

  // embedding + layer-0 QKV fused
  k_embqkv<<<(n + 63) / 64, 256, 0, stream>>>(x, Bemb, emb_b, h, L0, L0 + 1024,
                                              L0 + 2048, Qh, KVf8, n);

  // layer 0: attn -> post(+layer-1 QKV)
  k_attn<<<(n + 3) / 4, 256, 0, stream>>>(Qh, KVf8, rowp, srcs, aggrh, n);
  k_post<0><<<(n + 63) / 64, 256, 0, stream>>>(
      aggrh, h, L0 + 3072, bout, ln_g, ln_b, L0 + 4096, b1, L0 + 4608, b2,
      L1, L1 + 1024, L1 + 2048, Qh, KVf8, nullptr, nullptr, nullptr, n);

  // layer 1: attn -> post(+logits/log_softmax)
  k_attn<<<(n + 3) / 4, 256, 0, stream>>>(Qh, KVf8, rowp, srcs, aggrh, n);
  k_post<1><<<(n + 63) / 64, 256, 0, stream>>>(
      aggrh, h, L1 + 3072, bout + 64, ln_g + 64, ln_b + 64, L1 + 4096, b1 + 64,
      L1 + 4608, b2 + 64, nullptr, nullptr, nullptr, nullptr, nullptr,
      Bo, out_b, out, n);
}